// Round 15
// baseline (403.322 us; speedup 1.0000x reference)
//
#include <hip/hip_runtime.h>
#include <hip/hip_bf16.h>

// ---------------------------------------------------------------------------
// RGCN (basis decomposition) x4 layers + pair-scoring head.
//
// CSR build (bucket pipeline); memset via k_zero.
//
// Layer 0 (x is 64-dim, f32 input):
//   k_transform3<64> : MFMA GEMM -> hb2 (bf16x2 msg pairs) + self0 (f32[N,32])
//   k_aggregate0     : gather hb2 128B rows, acc += self0, tanh -> cat bf16
//
// Layers 1-3 (algebra swap + FUSED — R12 config, best measured; R14 showed
// split was 20us slower, fills were profiling artifacts):
//   k_layer_y : phase 1 aggregates y_b = sum_e comp[et,b]*h[src] (64B bf16
//               gathers) into registers -> bf16 into LDS A-tile [64x96];
//               phase 2 MFMA [A](K=96) @ [B0;B1;Wself] + bias, tanh -> cat.
//               LDS tiles use 104-u16 (208B) row stride: 20,000B total ->
//               8 blocks/CU (32 waves, was 6/24 at pow2+XOR) for the
//               latency-bound gather phase. __launch_bounds__(256,8).
//
// cat: bf16 [N,128] holds all 4 layer states. k_head: wave/pair dot+sigmoid.
// ---------------------------------------------------------------------------

#define SRC_MASK 0x3FFFFu
#define BUK_SH 9
#define BUK_W 512

typedef __attribute__((ext_vector_type(8))) short bf16x8;
typedef __attribute__((ext_vector_type(4))) float f32x4;
typedef unsigned short u16;
typedef unsigned int u32;

__device__ inline u32 f2bf(float f) {
    u32 u = __float_as_uint(f);
    return (u + 0x7FFFu + ((u >> 16) & 1u)) >> 16;
}
__device__ inline float bf2f(u32 lo16) { return __uint_as_float(lo16 << 16); }

__device__ inline float fast_tanh(float x) {
    float xc = fminf(fmaxf(x, -15.f), 15.f);
    float e = __expf(2.f * xc);
    return (e - 1.f) * __builtin_amdgcn_rcpf(e + 1.f);
}

__global__ void k_zero(int* __restrict__ p, int n) {
    int i = blockIdx.x * 256 + threadIdx.x;
    if (i < n) p[i] = 0;
}

// Exclusive scan in place of a[0..M), M%4==0, M/4 <= 256. 256-thread block.
__device__ inline void block_exscan(int* a, int M, int* wsum /*shared int[4]*/) {
    const int t = threadIdx.x;
    const int q = M >> 2;
    int s0 = 0, s1 = 0, s2 = 0, s3 = 0, s = 0;
    if (t < q) {
        s0 = a[4 * t]; s1 = a[4 * t + 1]; s2 = a[4 * t + 2]; s3 = a[4 * t + 3];
        s = s0 + s1 + s2 + s3;
    }
    int lane = t & 63, wid = t >> 6;
    int val = s;
    for (int d = 1; d < 64; d <<= 1) {
        int u = __shfl_up(val, d, 64);
        if (lane >= d) val += u;
    }
    if (lane == 63) wsum[wid] = val;
    __syncthreads();
    int woff = 0;
    for (int w = 0; w < wid; ++w) woff += wsum[w];
    val += woff;              // inclusive over block
    int base = val - s;       // exclusive base for this thread's 4 elems
    __syncthreads();
    if (t < q) {
        a[4 * t]     = base;
        a[4 * t + 1] = base + s0;
        a[4 * t + 2] = base + s0 + s1;
        a[4 * t + 3] = base + s0 + s1 + s2;
    }
    __syncthreads();
}

// ---- A: bucket histogram ----
__global__ __launch_bounds__(256) void k_buk_count(const int* __restrict__ dst,
                                                   int* __restrict__ gBukCnt, int E) {
    __shared__ int hist[1024];
    const int t = threadIdx.x;
    for (int f = t; f < 1024; f += 256) hist[f] = 0;
    __syncthreads();
    int e0 = blockIdx.x * 2048;
    for (int k = 0; k < 8; ++k) {
        int e = e0 + k * 256 + t;
        if (e < E) atomicAdd(&hist[dst[e] >> BUK_SH], 1);
    }
    __syncthreads();
    for (int f = t; f < 1024; f += 256) {
        int c = hist[f];
        if (c) atomicAdd(&gBukCnt[f], c);
    }
}

// ---- A2: scan bucket counts (1 block, 1024 threads; nb <= 1024) ----
__global__ void k_buk_scan(const int* __restrict__ gBukCnt, int* __restrict__ bukOff,
                           int nb) {
    __shared__ int lds[1024];
    int tid = threadIdx.x;
    int v = (tid < nb) ? gBukCnt[tid] : 0;
    lds[tid] = v;
    __syncthreads();
    for (int d = 1; d < 1024; d <<= 1) {
        int u = (tid >= d) ? lds[tid - d] : 0;
        __syncthreads();
        lds[tid] += u;
        __syncthreads();
    }
    if (tid < nb) bukOff[tid] = lds[tid] - v;       // exclusive
    if (tid == nb - 1) bukOff[nb] = lds[tid];       // total = E
}

// ---- B: block counting-sort by bucket + contiguous segment writeout ----
__global__ __launch_bounds__(256) void k_binscatter(
    const int* __restrict__ src, const int* __restrict__ dst,
    const int* __restrict__ etype, const int* __restrict__ bukOff,
    int* __restrict__ gBukCur, unsigned int* __restrict__ binned,
    int E, int NBUK)
{
    __shared__ int hist[1024];
    __shared__ int offs[1024];
    __shared__ int cur[1024];
    __shared__ int gb[1024];
    __shared__ int wsum[4];
    __shared__ unsigned int stage[2048];
    __shared__ unsigned short stageB[2048];   // bucket of each staged position
    const int t = threadIdx.x;
    for (int f = t; f < 1024; f += 256) { hist[f] = 0; cur[f] = 0; }
    __syncthreads();

    const int e0 = blockIdx.x * 2048;
    const int cntTot = min(2048, E - e0);
    unsigned int pk[8];
    int bk[8];
#pragma unroll
    for (int k = 0; k < 8; ++k) {
        int e = e0 + k * 256 + t;
        if (e < E) {
            int d = dst[e];
            bk[k] = d >> BUK_SH;
            pk[k] = (unsigned int)src[e]
                  | ((unsigned int)etype[e] << 29)
                  | ((unsigned int)(d & (BUK_W - 1)) << 20);
            atomicAdd(&hist[bk[k]], 1);
        } else bk[k] = -1;
    }
    __syncthreads();
    for (int f = t; f < 1024; f += 256) offs[f] = hist[f];
    __syncthreads();
    block_exscan(offs, 1024, wsum);
#pragma unroll
    for (int k = 0; k < 8; ++k) {
        if (bk[k] >= 0) {
            int pos = offs[bk[k]] + atomicAdd(&cur[bk[k]], 1);
            stage[pos] = pk[k];
            stageB[pos] = (unsigned short)bk[k];
        }
    }
    // reserve global space per bucket (one atomic per non-empty bucket)
    for (int f = t; f < NBUK; f += 256) {
        int c = hist[f];
        if (c > 0) gb[f] = bukOff[f] + atomicAdd(&gBukCur[f], c);
    }
    __syncthreads();
    // contiguous per-bucket segments
    for (int k = t; k < cntTot; k += 256) {
        int b = stageB[k];
        binned[(size_t)gb[b] + (size_t)(k - offs[b])] = stage[k];
    }
}

// ---- C: per-bucket finalize: rowptr + epack (all writes in 16KB window) ----
__global__ __launch_bounds__(256) void k_bucket_finalize(
    const unsigned int* __restrict__ binned, const int* __restrict__ bukOff,
    int* __restrict__ rowptr, unsigned int* __restrict__ epack, int N, int E)
{
    __shared__ int nhist[512];
    __shared__ int ncur[512];
    __shared__ int wsum[4];
    const int t = threadIdx.x;
    const int b = blockIdx.x;
    for (int f = t; f < 512; f += 256) { nhist[f] = 0; ncur[f] = 0; }
    __syncthreads();
    const int k0 = bukOff[b], k1 = bukOff[b + 1];
    for (int k = k0 + t; k < k1; k += 256)
        atomicAdd(&nhist[(binned[k] >> 20) & (BUK_W - 1)], 1);
    __syncthreads();
    block_exscan(nhist, 512, wsum);
    for (int f = t; f < 512; f += 256) {
        int node = (b << BUK_SH) + f;
        if (node < N) rowptr[node] = k0 + nhist[f];
    }
    if (b == 0 && t == 0) rowptr[N] = E;
    for (int k = k0 + t; k < k1; k += 256) {
        unsigned int v = binned[k];
        int dl = (v >> 20) & (BUK_W - 1);
        int pos = k0 + nhist[dl] + atomicAdd(&ncur[dl], 1);
        epack[pos] = v & 0xE003FFFFu;   // et[31:29] | src[17:0]
    }
}

// ---- MFMA transform, layer 0 ----
template<int DI>
__global__ __launch_bounds__(256) void k_transform3(
    const float* __restrict__ xin, int in_stride,
    const float* __restrict__ basis, const float* __restrict__ wself,
    const float* __restrict__ bias,
    u32* __restrict__ hb2, float* __restrict__ self0, int n)
{
    constexpr int ROWB = DI * 2;
    constexpr int SMASK = (ROWB / 16) - 1;
    constexpr int C4 = DI / 4;
    __shared__ u16 xs[64 * DI];
    __shared__ u16 bt[96 * DI];
    const int t = threadIdx.x;

    auto swz = [](int row, int byteInRow) -> int {
        int slot = (byteInRow >> 4) ^ ((row ^ (row >> 2)) & SMASK);
        return row * ROWB + (slot << 4) + (byteInRow & 15);
    };

    for (int f = t; f < 96 * C4; f += 256) {
        int k4 = f / 96;
        int o  = f - k4 * 96;
        const float* sp = (o < 64) ? (basis + (size_t)(o >> 5) * DI * 32 + (o & 31))
                                   : (wself + (o - 64));
        int k = 4 * k4;
        ushort4 pv;
        pv.x = (u16)f2bf(sp[(size_t)(k + 0) * 32]);
        pv.y = (u16)f2bf(sp[(size_t)(k + 1) * 32]);
        pv.z = (u16)f2bf(sp[(size_t)(k + 2) * 32]);
        pv.w = (u16)f2bf(sp[(size_t)(k + 3) * 32]);
        *(ushort4*)((char*)bt + swz(o, k * 2)) = pv;
    }

    const int node0 = blockIdx.x * 64;
    for (int f = t; f < 64 * C4; f += 256) {
        int nloc = f / C4, k4 = f - nloc * C4;
        int node = node0 + nloc;
        float4 v = make_float4(0.f, 0.f, 0.f, 0.f);
        if (node < n) v = *(const float4*)(xin + (size_t)node * in_stride + 4 * k4);
        ushort4 pv;
        pv.x = (u16)f2bf(v.x);
        pv.y = (u16)f2bf(v.y);
        pv.z = (u16)f2bf(v.z);
        pv.w = (u16)f2bf(v.w);
        *(ushort4*)((char*)xs + swz(nloc, 8 * k4)) = pv;
    }
    __syncthreads();

    const int w = t >> 6;
    const int l = t & 63;
    const int lr = l & 15;
    const int lg = l >> 4;

    f32x4 c[6];
#pragma unroll
    for (int i = 0; i < 6; ++i) c[i] = (f32x4){0.f, 0.f, 0.f, 0.f};

#pragma unroll
    for (int ks = 0; ks < DI / 32; ++ks) {
        const int kb = ks * 64 + lg * 16;
        bf16x8 a = *(const bf16x8*)((char*)xs + swz(w * 16 + lr, kb));
#pragma unroll
        for (int tt = 0; tt < 6; ++tt) {
            bf16x8 b = *(const bf16x8*)((char*)bt + swz(tt * 16 + lr, kb));
            c[tt] = __builtin_amdgcn_mfma_f32_16x16x32_bf16(a, b, c[tt], 0, 0, 0);
        }
    }

    const float bia0 = bias[lr];
    const float bia1 = bias[16 + lr];
#pragma unroll
    for (int r = 0; r < 4; ++r) {
        int node = node0 + w * 16 + lg * 4 + r;
        if (node < n) {
            hb2[(size_t)node * 32 + lr]      = f2bf(c[0][r]) | (f2bf(c[2][r]) << 16);
            hb2[(size_t)node * 32 + 16 + lr] = f2bf(c[1][r]) | (f2bf(c[3][r]) << 16);
            self0[(size_t)node * 32 + lr]      = c[4][r] + bia0;
            self0[(size_t)node * 32 + 16 + lr] = c[5][r] + bia1;
        }
    }
}

// ---- layer-0 aggregate: gather hb2 128B rows; epack shared via __shfl ----
template<int W>
__device__ __forceinline__ void agg0_block(
    const u32* __restrict__ hb2, const u32* __restrict__ epack,
    int k, int oj, unsigned gbase, const u32* cw, float4& acc)
{
    int pa;
    if (W == 8)      pa = (int)epack[k + oj];
    else if (W == 4) pa = (int)epack[k + (oj & 3)];
    else if (W == 2) pa = (int)epack[k + (oj & 1)];
    else             pa = (int)epack[k];
    u32 pp[W];
    uint4 hh[W];
#pragma unroll
    for (int j = 0; j < W; ++j) {
        pp[j] = (W > 1) ? (u32)__shfl(pa, j, 8) : (u32)pa;
        unsigned boff = (pp[j] & SRC_MASK) * 128u + gbase;
        hh[j] = *(const uint4*)((const char*)hb2 + boff);
    }
#pragma unroll
    for (int j = 0; j < W; ++j) {
        u32 w = cw[pp[j] >> 29];
        float w0 = __uint_as_float(w << 16);
        float w1 = __uint_as_float(w & 0xFFFF0000u);
        acc.x = fmaf(w0, __uint_as_float(hh[j].x << 16), acc.x);
        acc.x = fmaf(w1, __uint_as_float(hh[j].x & 0xFFFF0000u), acc.x);
        acc.y = fmaf(w0, __uint_as_float(hh[j].y << 16), acc.y);
        acc.y = fmaf(w1, __uint_as_float(hh[j].y & 0xFFFF0000u), acc.y);
        acc.z = fmaf(w0, __uint_as_float(hh[j].z << 16), acc.z);
        acc.z = fmaf(w1, __uint_as_float(hh[j].z & 0xFFFF0000u), acc.z);
        acc.w = fmaf(w0, __uint_as_float(hh[j].w << 16), acc.w);
        acc.w = fmaf(w1, __uint_as_float(hh[j].w & 0xFFFF0000u), acc.w);
    }
}

__global__ __launch_bounds__(256) void k_aggregate0(
    const u32* __restrict__ hb2,
    const u32* __restrict__ epack,
    const int* __restrict__ rowptr,
    const float* __restrict__ comp,   // [8,2]
    const float* __restrict__ self0,  // [N,32] f32
    u16* __restrict__ cat0,           // cat cols 0..31 (row stride 128 u16)
    int n)
{
    __shared__ u32 cw[8];
    if (threadIdx.x < 8)
        cw[threadIdx.x] = f2bf(comp[threadIdx.x * 2 + 0])
                        | (f2bf(comp[threadIdx.x * 2 + 1]) << 16);
    __syncthreads();
    int t = blockIdx.x * 256 + threadIdx.x;
    int node = t >> 3;
    int oj = t & 7;
    if (node >= n) return;
    float4 acc = *(const float4*)(self0 + (size_t)node * 32 + 4 * oj);
    int k = rowptr[node];
    const int k1 = rowptr[node + 1];
    const unsigned gbase = (unsigned)oj * 16u;

    while (k + 8 <= k1) { agg0_block<8>(hb2, epack, k, oj, gbase, cw, acc); k += 8; }
    const int r = k1 - k;
    if (r & 4) { agg0_block<4>(hb2, epack, k, oj, gbase, cw, acc); k += 4; }
    if (r & 2) { agg0_block<2>(hb2, epack, k, oj, gbase, cw, acc); k += 2; }
    if (r & 1) { agg0_block<1>(hb2, epack, k, oj, gbase, cw, acc); }

    ushort4 o;
    o.x = (u16)f2bf(fast_tanh(acc.x));
    o.y = (u16)f2bf(fast_tanh(acc.y));
    o.z = (u16)f2bf(fast_tanh(acc.z));
    o.w = (u16)f2bf(fast_tanh(acc.w));
    *(ushort4*)(cat0 + (size_t)node * 128 + 4 * oj) = o;
}

// ---- layers 1-3 FUSED: aggregate y (64B gathers) -> LDS -> MFMA -> tanh ----
template<int W>
__device__ __forceinline__ void aggy_block(
    const u16* __restrict__ catPrev, const u32* __restrict__ epack,
    int k, int i, unsigned gbase, const u32* cw, float* y0, float* y1)
{
    int pa, pb = 0;
    if (W == 8)      { pa = (int)epack[k + i]; pb = (int)epack[k + 4 + i]; }
    else if (W == 4)   pa = (int)epack[k + i];
    else if (W == 2)   pa = (int)epack[k + (i & 1)];
    else               pa = (int)epack[k];
    u32 pp[W];
    uint4 hh[W];
#pragma unroll
    for (int j = 0; j < W; ++j) {
        int v;
        if (W == 8)      v = (j < 4) ? __shfl(pa, j, 4) : __shfl(pb, j - 4, 4);
        else if (W > 1)  v = __shfl(pa, j, 4);
        else             v = pa;
        pp[j] = (u32)v;
        unsigned boff = (pp[j] & SRC_MASK) * 256u + gbase;
        hh[j] = *(const uint4*)((const char*)catPrev + boff);
    }
#pragma unroll
    for (int j = 0; j < W; ++j) {
        u32 w = cw[pp[j] >> 29];
        float w0 = __uint_as_float(w << 16);
        float w1 = __uint_as_float(w & 0xFFFF0000u);
        const u32* hp = (const u32*)&hh[j];
#pragma unroll
        for (int m = 0; m < 4; ++m) {
            u32 pair = hp[m];
            float ha = __uint_as_float(pair << 16);
            float hb = __uint_as_float(pair & 0xFFFF0000u);
            y0[2 * m]     = fmaf(w0, ha, y0[2 * m]);
            y1[2 * m]     = fmaf(w1, ha, y1[2 * m]);
            y0[2 * m + 1] = fmaf(w0, hb, y0[2 * m + 1]);
            y1[2 * m + 1] = fmaf(w1, hb, y1[2 * m + 1]);
        }
    }
}

// LDS row stride = 104 u16 (208B = 13x16B slots). 96 u16 content + 8 pad.
// Odd stride rotates row-start banks (20*r mod 32, period 8) -> <=2-way
// conflicts on staging/y-writes; ~8-way only on the 9 MFMA b128 reads
// (negligible vs gather phase). Total LDS 20,000B -> 8 blocks/CU (32 waves).
__global__ __launch_bounds__(256, 8) void k_layer_y(
    const u16* __restrict__ catPrev,  // cat + (l-1)*32, row stride 128 u16
    const u32* __restrict__ epack,
    const int* __restrict__ rowptr,
    const float* __restrict__ comp,   // [8,2]
    const float* __restrict__ basis,  // [2,32,32]
    const float* __restrict__ wself,  // [32,32]
    const float* __restrict__ bias,   // [32]
    u16* __restrict__ catOut,         // cat + l*32, row stride 128
    int n)
{
    __shared__ u16 xs[64 * 104];      // A tile [64 nodes][96 kk] (+8 pad)
    __shared__ u16 bt[32 * 104];      // B^T tile
    __shared__ u32 cw[8];
    const int t = threadIdx.x;

    if (t < 8) cw[t] = f2bf(comp[2 * t]) | (f2bf(comp[2 * t + 1]) << 16);

    // stage B^T: bt[o][kk]: kk<32 -> B0[kk,o]; 32..63 -> B1; 64..95 -> Wself
    for (int f = t; f < 32 * 12; f += 256) {
        int c8 = f >> 5, o = f & 31;
        u32 pk[4];
#pragma unroll
        for (int e = 0; e < 4; ++e) {
            int k0 = c8 * 8 + 2 * e, k1v = k0 + 1;
            float v0 = (k0 < 64) ? basis[(size_t)(k0 >> 5) * 1024 + (k0 & 31) * 32 + o]
                                 : wself[(size_t)(k0 - 64) * 32 + o];
            float v1 = (k1v < 64) ? basis[(size_t)(k1v >> 5) * 1024 + (k1v & 31) * 32 + o]
                                  : wself[(size_t)(k1v - 64) * 32 + o];
            pk[e] = f2bf(v0) | (f2bf(v1) << 16);
        }
        *(uint4*)(bt + o * 104 + c8 * 8) = *(uint4*)pk;
    }

    // ---- phase 1: aggregate (4 lanes/node, 8 dims each) ----
    const int node0 = blockIdx.x * 64;
    const int nloc = t >> 2;
    const int i = t & 3;
    const int node = node0 + nloc;

    // stage own h chunk (kk 64..95): thread (nloc,i) covers 8 dims
    {
        uint4 v = make_uint4(0u, 0u, 0u, 0u);
        if (node < n) v = *(const uint4*)(catPrev + (size_t)node * 128 + i * 8);
        *(uint4*)(xs + nloc * 104 + (8 + i) * 8) = v;
    }
    __syncthreads();   // cw visible to all; xs h-chunks in place

    float y0[8], y1[8];
#pragma unroll
    for (int m = 0; m < 8; ++m) { y0[m] = 0.f; y1[m] = 0.f; }
    if (node < n) {
        int k = rowptr[node];
        const int k1 = rowptr[node + 1];
        const unsigned gbase = (unsigned)i * 16u;
        while (k + 8 <= k1) { aggy_block<8>(catPrev, epack, k, i, gbase, cw, y0, y1); k += 8; }
        const int r = k1 - k;
        if (r & 4) { aggy_block<4>(catPrev, epack, k, i, gbase, cw, y0, y1); k += 4; }
        if (r & 2) { aggy_block<2>(catPrev, epack, k, i, gbase, cw, y0, y1); k += 2; }
        if (r & 1) { aggy_block<1>(catPrev, epack, k, i, gbase, cw, y0, y1); }
    }
    // y0 -> kk i*8..i*8+7 (chunk i); y1 -> kk 32+i*8.. (chunk 4+i)
    {
        uint4 o0, o1;
        o0.x = f2bf(y0[0]) | (f2bf(y0[1]) << 16);
        o0.y = f2bf(y0[2]) | (f2bf(y0[3]) << 16);
        o0.z = f2bf(y0[4]) | (f2bf(y0[5]) << 16);
        o0.w = f2bf(y0[6]) | (f2bf(y0[7]) << 16);
        o1.x = f2bf(y1[0]) | (f2bf(y1[1]) << 16);
        o1.y = f2bf(y1[2]) | (f2bf(y1[3]) << 16);
        o1.z = f2bf(y1[4]) | (f2bf(y1[5]) << 16);
        o1.w = f2bf(y1[6]) | (f2bf(y1[7]) << 16);
        *(uint4*)(xs + nloc * 104 + i * 8) = o0;
        *(uint4*)(xs + nloc * 104 + (4 + i) * 8) = o1;
    }
    __syncthreads();

    // ---- phase 2: MFMA [64x96] @ [96x32] ----
    const int w = t >> 6;
    const int l = t & 63;
    const int lr = l & 15;
    const int lg = l >> 4;

    f32x4 c0 = (f32x4){0.f, 0.f, 0.f, 0.f};
    f32x4 c1 = (f32x4){0.f, 0.f, 0.f, 0.f};
#pragma unroll
    for (int ks = 0; ks < 3; ++ks) {
        const int ch = ks * 4 + lg;           // chunk 0..11
        bf16x8 a  = *(const bf16x8*)(xs + (w * 16 + lr) * 104 + ch * 8);
        bf16x8 b0 = *(const bf16x8*)(bt + lr * 104 + ch * 8);
        bf16x8 b1 = *(const bf16x8*)(bt + (16 + lr) * 104 + ch * 8);
        c0 = __builtin_amdgcn_mfma_f32_16x16x32_bf16(a, b0, c0, 0, 0, 0);
        c1 = __builtin_amdgcn_mfma_f32_16x16x32_bf16(a, b1, c1, 0, 0, 0);
    }

    const float bia0 = bias[lr];
    const float bia1 = bias[16 + lr];
#pragma unroll
    for (int r = 0; r < 4; ++r) {
        int nodeW = node0 + w * 16 + lg * 4 + r;
        if (nodeW < n) {
            catOut[(size_t)nodeW * 128 + lr]      = (u16)f2bf(fast_tanh(c0[r] + bia0));
            catOut[(size_t)nodeW * 128 + 16 + lr] = (u16)f2bf(fast_tanh(c1[r] + bia1));
        }
    }
}

// ---- head: one wave per pair, 256-dim dot (bf16 cat) + sigmoid ----
__global__ void k_head(const u16* __restrict__ cat, const int* __restrict__ uidx,
                       const int* __restrict__ iidx, const float* __restrict__ w,
                       const float* __restrict__ b, float* __restrict__ out, int B) {
    int p = blockIdx.x;
    if (p >= B) return;
    int lane = threadIdx.x;  // 0..63
    const u16* cu = cat + (size_t)uidx[p] * 128;
    const u16* ci = cat + (size_t)iidx[p] * 128;
    float s = 0.f;
    s = fmaf(bf2f(cu[lane]), w[lane], s);
    s = fmaf(bf2f(cu[lane + 64]), w[lane + 64], s);
    s = fmaf(bf2f(ci[lane]), w[lane + 128], s);
    s = fmaf(bf2f(ci[lane + 64]), w[lane + 192], s);
    for (int d = 32; d > 0; d >>= 1) s += __shfl_down(s, d, 64);
    if (lane == 0) out[p] = 1.f / (1.f + expf(-(s + b[0])));
}

extern "C" void kernel_launch(void* const* d_in, const int* in_sizes, int n_in,
                              void* d_out, int out_size, void* d_ws, size_t ws_size,
                              hipStream_t stream) {
    const float* x      = (const float*)d_in[0];
    const int*   src    = (const int*)d_in[1];
    const int*   dst    = (const int*)d_in[2];
    const int*   etype  = (const int*)d_in[3];
    const int*   uidx   = (const int*)d_in[4];
    const int*   iidx   = (const int*)d_in[5];
    const float* lin1_w = (const float*)d_in[22];
    const float* lin1_b = (const float*)d_in[23];

    const int N = in_sizes[0] / 64;
    const int E = in_sizes[1];
    const int B = in_sizes[4];
    const int NBUK = (N + BUK_W - 1) >> BUK_SH;

    // workspace carve-out (256B aligned)
    char* p = (char*)d_ws;
    auto alloc = [&](size_t bytes) -> void* {
        void* r = (void*)p;
        p += (bytes + 255) & ~(size_t)255;
        return r;
    };
    u32*   hb2     = (u32*)alloc((size_t)N * 32 * sizeof(u32));
    float* self0   = (float*)alloc((size_t)N * 32 * sizeof(float));
    u16*   cat     = (u16*)alloc((size_t)N * 128 * sizeof(u16));
    int*   rowptr  = (int*)alloc((size_t)(N + 1) * sizeof(int));
    u32*   epack   = (u32*)alloc((size_t)E * sizeof(u32));
    u32*   binned  = (u32*)alloc((size_t)E * sizeof(u32));
    int*   gBukCnt = (int*)alloc(1024 * sizeof(int));
    int*   gBukCur = (int*)alloc(1024 * sizeof(int));  // adjacent to gBukCnt
    int*   bukOff  = (int*)alloc(1025 * sizeof(int));

    // ---- CSR build (bucket pipeline) ----
    k_zero<<<8, 256, 0, stream>>>(gBukCnt, 2048);   // gBukCnt + gBukCur
    int ebGrid = (E + 2047) / 2048;
    k_buk_count<<<ebGrid, 256, 0, stream>>>(dst, gBukCnt, E);
    k_buk_scan<<<1, 1024, 0, stream>>>(gBukCnt, bukOff, NBUK);
    k_binscatter<<<ebGrid, 256, 0, stream>>>(src, dst, etype, bukOff, gBukCur,
                                             binned, E, NBUK);
    k_bucket_finalize<<<NBUK, 256, 0, stream>>>(binned, bukOff, rowptr, epack, N, E);

    const int tr_grid = (N + 63) / 64;

    // ---- layer 0: transform -> aggregate (x is 64-dim) ----
    k_transform3<64><<<tr_grid, 256, 0, stream>>>(
        x, 64, (const float*)d_in[6], (const float*)d_in[8], (const float*)d_in[9],
        hb2, self0, N);
    k_aggregate0<<<(N * 8 + 255) / 256, 256, 0, stream>>>(
        hb2, epack, rowptr, (const float*)d_in[7], self0, cat, N);

    // ---- layers 1-3: fused aggregate+transform ----
    for (int l = 1; l < 4; ++l) {
        k_layer_y<<<tr_grid, 256, 0, stream>>>(
            cat + (size_t)(l - 1) * 32, epack, rowptr,
            (const float*)d_in[7 + l * 4], (const float*)d_in[6 + l * 4],
            (const float*)d_in[8 + l * 4], (const float*)d_in[9 + l * 4],
            cat + (size_t)l * 32, N);
    }

    // ---- head ----
    k_head<<<B, 64, 0, stream>>>(cat, uidx, iidx, lin1_w, lin1_b, (float*)d_out, B);
}

// Round 16
// 403.071 us; speedup vs baseline: 1.0006x; 1.0006x over previous
//
#include <hip/hip_runtime.h>
#include <hip/hip_bf16.h>

// ---------------------------------------------------------------------------
// RGCN (basis decomposition) x4 layers + pair-scoring head.
//
// CSR build (bucket pipeline); memset via k_zero.
//
// Layer 0 (x is 64-dim, f32 input):
//   k_transform3<64> : MFMA GEMM -> hb2 (bf16x2 msg pairs) + self0 (f32[N,32])
//   k_aggregate0     : gather hb2 128B rows, acc += self0, tanh -> cat bf16
//
// Layers 1-3 (algebra swap + FUSED — R12 config, best measured; R14 showed
// split was 20us slower, fills were profiling artifacts):
//   k_layer_y : phase 1 aggregates y_b = sum_e comp[et,b]*h[src] (64B bf16
//               gathers) into registers -> bf16 into LDS A-tile [64x96];
//               phase 2 MFMA [A](K=96) @ [B0;B1;Wself] + bias, tanh -> cat.
//               LDS tiles use 104-u16 (208B) row stride: 20,000B total ->
//               8 blocks/CU (32 waves, was 6/24 at pow2+XOR) for the
//               latency-bound gather phase. __launch_bounds__(256,8).
//
// cat: bf16 [N,128] holds all 4 layer states. k_head: wave/pair dot+sigmoid.
// ---------------------------------------------------------------------------

#define SRC_MASK 0x3FFFFu
#define BUK_SH 9
#define BUK_W 512

typedef __attribute__((ext_vector_type(8))) short bf16x8;
typedef __attribute__((ext_vector_type(4))) float f32x4;
typedef unsigned short u16;
typedef unsigned int u32;

__device__ inline u32 f2bf(float f) {
    u32 u = __float_as_uint(f);
    return (u + 0x7FFFu + ((u >> 16) & 1u)) >> 16;
}
__device__ inline float bf2f(u32 lo16) { return __uint_as_float(lo16 << 16); }

__device__ inline float fast_tanh(float x) {
    float xc = fminf(fmaxf(x, -15.f), 15.f);
    float e = __expf(2.f * xc);
    return (e - 1.f) * __builtin_amdgcn_rcpf(e + 1.f);
}

__global__ void k_zero(int* __restrict__ p, int n) {
    int i = blockIdx.x * 256 + threadIdx.x;
    if (i < n) p[i] = 0;
}

// Exclusive scan in place of a[0..M), M%4==0, M/4 <= 256. 256-thread block.
__device__ inline void block_exscan(int* a, int M, int* wsum /*shared int[4]*/) {
    const int t = threadIdx.x;
    const int q = M >> 2;
    int s0 = 0, s1 = 0, s2 = 0, s3 = 0, s = 0;
    if (t < q) {
        s0 = a[4 * t]; s1 = a[4 * t + 1]; s2 = a[4 * t + 2]; s3 = a[4 * t + 3];
        s = s0 + s1 + s2 + s3;
    }
    int lane = t & 63, wid = t >> 6;
    int val = s;
    for (int d = 1; d < 64; d <<= 1) {
        int u = __shfl_up(val, d, 64);
        if (lane >= d) val += u;
    }
    if (lane == 63) wsum[wid] = val;
    __syncthreads();
    int woff = 0;
    for (int w = 0; w < wid; ++w) woff += wsum[w];
    val += woff;              // inclusive over block
    int base = val - s;       // exclusive base for this thread's 4 elems
    __syncthreads();
    if (t < q) {
        a[4 * t]     = base;
        a[4 * t + 1] = base + s0;
        a[4 * t + 2] = base + s0 + s1;
        a[4 * t + 3] = base + s0 + s1 + s2;
    }
    __syncthreads();
}

// ---- A: bucket histogram ----
__global__ __launch_bounds__(256) void k_buk_count(const int* __restrict__ dst,
                                                   int* __restrict__ gBukCnt, int E) {
    __shared__ int hist[1024];
    const int t = threadIdx.x;
    for (int f = t; f < 1024; f += 256) hist[f] = 0;
    __syncthreads();
    int e0 = blockIdx.x * 2048;
    for (int k = 0; k < 8; ++k) {
        int e = e0 + k * 256 + t;
        if (e < E) atomicAdd(&hist[dst[e] >> BUK_SH], 1);
    }
    __syncthreads();
    for (int f = t; f < 1024; f += 256) {
        int c = hist[f];
        if (c) atomicAdd(&gBukCnt[f], c);
    }
}

// ---- A2: scan bucket counts (1 block, 1024 threads; nb <= 1024) ----
__global__ void k_buk_scan(const int* __restrict__ gBukCnt, int* __restrict__ bukOff,
                           int nb) {
    __shared__ int lds[1024];
    int tid = threadIdx.x;
    int v = (tid < nb) ? gBukCnt[tid] : 0;
    lds[tid] = v;
    __syncthreads();
    for (int d = 1; d < 1024; d <<= 1) {
        int u = (tid >= d) ? lds[tid - d] : 0;
        __syncthreads();
        lds[tid] += u;
        __syncthreads();
    }
    if (tid < nb) bukOff[tid] = lds[tid] - v;       // exclusive
    if (tid == nb - 1) bukOff[nb] = lds[tid];       // total = E
}

// ---- B: block counting-sort by bucket + contiguous segment writeout ----
__global__ __launch_bounds__(256) void k_binscatter(
    const int* __restrict__ src, const int* __restrict__ dst,
    const int* __restrict__ etype, const int* __restrict__ bukOff,
    int* __restrict__ gBukCur, unsigned int* __restrict__ binned,
    int E, int NBUK)
{
    __shared__ int hist[1024];
    __shared__ int offs[1024];
    __shared__ int cur[1024];
    __shared__ int gb[1024];
    __shared__ int wsum[4];
    __shared__ unsigned int stage[2048];
    __shared__ unsigned short stageB[2048];   // bucket of each staged position
    const int t = threadIdx.x;
    for (int f = t; f < 1024; f += 256) { hist[f] = 0; cur[f] = 0; }
    __syncthreads();

    const int e0 = blockIdx.x * 2048;
    const int cntTot = min(2048, E - e0);
    unsigned int pk[8];
    int bk[8];
#pragma unroll
    for (int k = 0; k < 8; ++k) {
        int e = e0 + k * 256 + t;
        if (e < E) {
            int d = dst[e];
            bk[k] = d >> BUK_SH;
            pk[k] = (unsigned int)src[e]
                  | ((unsigned int)etype[e] << 29)
                  | ((unsigned int)(d & (BUK_W - 1)) << 20);
            atomicAdd(&hist[bk[k]], 1);
        } else bk[k] = -1;
    }
    __syncthreads();
    for (int f = t; f < 1024; f += 256) offs[f] = hist[f];
    __syncthreads();
    block_exscan(offs, 1024, wsum);
#pragma unroll
    for (int k = 0; k < 8; ++k) {
        if (bk[k] >= 0) {
            int pos = offs[bk[k]] + atomicAdd(&cur[bk[k]], 1);
            stage[pos] = pk[k];
            stageB[pos] = (unsigned short)bk[k];
        }
    }
    // reserve global space per bucket (one atomic per non-empty bucket)
    for (int f = t; f < NBUK; f += 256) {
        int c = hist[f];
        if (c > 0) gb[f] = bukOff[f] + atomicAdd(&gBukCur[f], c);
    }
    __syncthreads();
    // contiguous per-bucket segments
    for (int k = t; k < cntTot; k += 256) {
        int b = stageB[k];
        binned[(size_t)gb[b] + (size_t)(k - offs[b])] = stage[k];
    }
}

// ---- C: per-bucket finalize: rowptr + epack (all writes in 16KB window) ----
__global__ __launch_bounds__(256) void k_bucket_finalize(
    const unsigned int* __restrict__ binned, const int* __restrict__ bukOff,
    int* __restrict__ rowptr, unsigned int* __restrict__ epack, int N, int E)
{
    __shared__ int nhist[512];
    __shared__ int ncur[512];
    __shared__ int wsum[4];
    const int t = threadIdx.x;
    const int b = blockIdx.x;
    for (int f = t; f < 512; f += 256) { nhist[f] = 0; ncur[f] = 0; }
    __syncthreads();
    const int k0 = bukOff[b], k1 = bukOff[b + 1];
    for (int k = k0 + t; k < k1; k += 256)
        atomicAdd(&nhist[(binned[k] >> 20) & (BUK_W - 1)], 1);
    __syncthreads();
    block_exscan(nhist, 512, wsum);
    for (int f = t; f < 512; f += 256) {
        int node = (b << BUK_SH) + f;
        if (node < N) rowptr[node] = k0 + nhist[f];
    }
    if (b == 0 && t == 0) rowptr[N] = E;
    for (int k = k0 + t; k < k1; k += 256) {
        unsigned int v = binned[k];
        int dl = (v >> 20) & (BUK_W - 1);
        int pos = k0 + nhist[dl] + atomicAdd(&ncur[dl], 1);
        epack[pos] = v & 0xE003FFFFu;   // et[31:29] | src[17:0]
    }
}

// ---- MFMA transform, layer 0 ----
template<int DI>
__global__ __launch_bounds__(256) void k_transform3(
    const float* __restrict__ xin, int in_stride,
    const float* __restrict__ basis, const float* __restrict__ wself,
    const float* __restrict__ bias,
    u32* __restrict__ hb2, float* __restrict__ self0, int n)
{
    constexpr int ROWB = DI * 2;
    constexpr int SMASK = (ROWB / 16) - 1;
    constexpr int C4 = DI / 4;
    __shared__ u16 xs[64 * DI];
    __shared__ u16 bt[96 * DI];
    const int t = threadIdx.x;

    auto swz = [](int row, int byteInRow) -> int {
        int slot = (byteInRow >> 4) ^ ((row ^ (row >> 2)) & SMASK);
        return row * ROWB + (slot << 4) + (byteInRow & 15);
    };

    for (int f = t; f < 96 * C4; f += 256) {
        int k4 = f / 96;
        int o  = f - k4 * 96;
        const float* sp = (o < 64) ? (basis + (size_t)(o >> 5) * DI * 32 + (o & 31))
                                   : (wself + (o - 64));
        int k = 4 * k4;
        ushort4 pv;
        pv.x = (u16)f2bf(sp[(size_t)(k + 0) * 32]);
        pv.y = (u16)f2bf(sp[(size_t)(k + 1) * 32]);
        pv.z = (u16)f2bf(sp[(size_t)(k + 2) * 32]);
        pv.w = (u16)f2bf(sp[(size_t)(k + 3) * 32]);
        *(ushort4*)((char*)bt + swz(o, k * 2)) = pv;
    }

    const int node0 = blockIdx.x * 64;
    for (int f = t; f < 64 * C4; f += 256) {
        int nloc = f / C4, k4 = f - nloc * C4;
        int node = node0 + nloc;
        float4 v = make_float4(0.f, 0.f, 0.f, 0.f);
        if (node < n) v = *(const float4*)(xin + (size_t)node * in_stride + 4 * k4);
        ushort4 pv;
        pv.x = (u16)f2bf(v.x);
        pv.y = (u16)f2bf(v.y);
        pv.z = (u16)f2bf(v.z);
        pv.w = (u16)f2bf(v.w);
        *(ushort4*)((char*)xs + swz(nloc, 8 * k4)) = pv;
    }
    __syncthreads();

    const int w = t >> 6;
    const int l = t & 63;
    const int lr = l & 15;
    const int lg = l >> 4;

    f32x4 c[6];
#pragma unroll
    for (int i = 0; i < 6; ++i) c[i] = (f32x4){0.f, 0.f, 0.f, 0.f};

#pragma unroll
    for (int ks = 0; ks < DI / 32; ++ks) {
        const int kb = ks * 64 + lg * 16;
        bf16x8 a = *(const bf16x8*)((char*)xs + swz(w * 16 + lr, kb));
#pragma unroll
        for (int tt = 0; tt < 6; ++tt) {
            bf16x8 b = *(const bf16x8*)((char*)bt + swz(tt * 16 + lr, kb));
            c[tt] = __builtin_amdgcn_mfma_f32_16x16x32_bf16(a, b, c[tt], 0, 0, 0);
        }
    }

    const float bia0 = bias[lr];
    const float bia1 = bias[16 + lr];
#pragma unroll
    for (int r = 0; r < 4; ++r) {
        int node = node0 + w * 16 + lg * 4 + r;
        if (node < n) {
            hb2[(size_t)node * 32 + lr]      = f2bf(c[0][r]) | (f2bf(c[2][r]) << 16);
            hb2[(size_t)node * 32 + 16 + lr] = f2bf(c[1][r]) | (f2bf(c[3][r]) << 16);
            self0[(size_t)node * 32 + lr]      = c[4][r] + bia0;
            self0[(size_t)node * 32 + 16 + lr] = c[5][r] + bia1;
        }
    }
}

// ---- layer-0 aggregate: gather hb2 128B rows; epack shared via __shfl ----
template<int W>
__device__ __forceinline__ void agg0_block(
    const u32* __restrict__ hb2, const u32* __restrict__ epack,
    int k, int oj, unsigned gbase, const u32* cw, float4& acc)
{
    int pa;
    if (W == 8)      pa = (int)epack[k + oj];
    else if (W == 4) pa = (int)epack[k + (oj & 3)];
    else if (W == 2) pa = (int)epack[k + (oj & 1)];
    else             pa = (int)epack[k];
    u32 pp[W];
    uint4 hh[W];
#pragma unroll
    for (int j = 0; j < W; ++j) {
        pp[j] = (W > 1) ? (u32)__shfl(pa, j, 8) : (u32)pa;
        unsigned boff = (pp[j] & SRC_MASK) * 128u + gbase;
        hh[j] = *(const uint4*)((const char*)hb2 + boff);
    }
#pragma unroll
    for (int j = 0; j < W; ++j) {
        u32 w = cw[pp[j] >> 29];
        float w0 = __uint_as_float(w << 16);
        float w1 = __uint_as_float(w & 0xFFFF0000u);
        acc.x = fmaf(w0, __uint_as_float(hh[j].x << 16), acc.x);
        acc.x = fmaf(w1, __uint_as_float(hh[j].x & 0xFFFF0000u), acc.x);
        acc.y = fmaf(w0, __uint_as_float(hh[j].y << 16), acc.y);
        acc.y = fmaf(w1, __uint_as_float(hh[j].y & 0xFFFF0000u), acc.y);
        acc.z = fmaf(w0, __uint_as_float(hh[j].z << 16), acc.z);
        acc.z = fmaf(w1, __uint_as_float(hh[j].z & 0xFFFF0000u), acc.z);
        acc.w = fmaf(w0, __uint_as_float(hh[j].w << 16), acc.w);
        acc.w = fmaf(w1, __uint_as_float(hh[j].w & 0xFFFF0000u), acc.w);
    }
}

__global__ __launch_bounds__(256) void k_aggregate0(
    const u32* __restrict__ hb2,
    const u32* __restrict__ epack,
    const int* __restrict__ rowptr,
    const float* __restrict__ comp,   // [8,2]
    const float* __restrict__ self0,  // [N,32] f32
    u16* __restrict__ cat0,           // cat cols 0..31 (row stride 128 u16)
    int n)
{
    __shared__ u32 cw[8];
    if (threadIdx.x < 8)
        cw[threadIdx.x] = f2bf(comp[threadIdx.x * 2 + 0])
                        | (f2bf(comp[threadIdx.x * 2 + 1]) << 16);
    __syncthreads();
    int t = blockIdx.x * 256 + threadIdx.x;
    int node = t >> 3;
    int oj = t & 7;
    if (node >= n) return;
    float4 acc = *(const float4*)(self0 + (size_t)node * 32 + 4 * oj);
    int k = rowptr[node];
    const int k1 = rowptr[node + 1];
    const unsigned gbase = (unsigned)oj * 16u;

    while (k + 8 <= k1) { agg0_block<8>(hb2, epack, k, oj, gbase, cw, acc); k += 8; }
    const int r = k1 - k;
    if (r & 4) { agg0_block<4>(hb2, epack, k, oj, gbase, cw, acc); k += 4; }
    if (r & 2) { agg0_block<2>(hb2, epack, k, oj, gbase, cw, acc); k += 2; }
    if (r & 1) { agg0_block<1>(hb2, epack, k, oj, gbase, cw, acc); }

    ushort4 o;
    o.x = (u16)f2bf(fast_tanh(acc.x));
    o.y = (u16)f2bf(fast_tanh(acc.y));
    o.z = (u16)f2bf(fast_tanh(acc.z));
    o.w = (u16)f2bf(fast_tanh(acc.w));
    *(ushort4*)(cat0 + (size_t)node * 128 + 4 * oj) = o;
}

// ---- layers 1-3 FUSED: aggregate y (64B gathers) -> LDS -> MFMA -> tanh ----
template<int W>
__device__ __forceinline__ void aggy_block(
    const u16* __restrict__ catPrev, const u32* __restrict__ epack,
    int k, int i, unsigned gbase, const u32* cw, float* y0, float* y1)
{
    int pa, pb = 0;
    if (W == 8)      { pa = (int)epack[k + i]; pb = (int)epack[k + 4 + i]; }
    else if (W == 4)   pa = (int)epack[k + i];
    else if (W == 2)   pa = (int)epack[k + (i & 1)];
    else               pa = (int)epack[k];
    u32 pp[W];
    uint4 hh[W];
#pragma unroll
    for (int j = 0; j < W; ++j) {
        int v;
        if (W == 8)      v = (j < 4) ? __shfl(pa, j, 4) : __shfl(pb, j - 4, 4);
        else if (W > 1)  v = __shfl(pa, j, 4);
        else             v = pa;
        pp[j] = (u32)v;
        unsigned boff = (pp[j] & SRC_MASK) * 256u + gbase;
        hh[j] = *(const uint4*)((const char*)catPrev + boff);
    }
#pragma unroll
    for (int j = 0; j < W; ++j) {
        u32 w = cw[pp[j] >> 29];
        float w0 = __uint_as_float(w << 16);
        float w1 = __uint_as_float(w & 0xFFFF0000u);
        const u32* hp = (const u32*)&hh[j];
#pragma unroll
        for (int m = 0; m < 4; ++m) {
            u32 pair = hp[m];
            float ha = __uint_as_float(pair << 16);
            float hb = __uint_as_float(pair & 0xFFFF0000u);
            y0[2 * m]     = fmaf(w0, ha, y0[2 * m]);
            y1[2 * m]     = fmaf(w1, ha, y1[2 * m]);
            y0[2 * m + 1] = fmaf(w0, hb, y0[2 * m + 1]);
            y1[2 * m + 1] = fmaf(w1, hb, y1[2 * m + 1]);
        }
    }
}

// LDS row stride = 104 u16 (208B = 13x16B slots). 96 u16 content + 8 pad.
// Odd stride rotates row-start banks (20*r mod 32, period 8) -> <=2-way
// conflicts on staging/y-writes; ~8-way only on the 9 MFMA b128 reads
// (negligible vs gather phase). Total LDS 20,000B -> 8 blocks/CU (32 waves).
__global__ __launch_bounds__(256, 8) void k_layer_y(
    const u16* __restrict__ catPrev,  // cat + (l-1)*32, row stride 128 u16
    const u32* __restrict__ epack,
    const int* __restrict__ rowptr,
    const float* __restrict__ comp,   // [8,2]
    const float* __restrict__ basis,  // [2,32,32]
    const float* __restrict__ wself,  // [32,32]
    const float* __restrict__ bias,   // [32]
    u16* __restrict__ catOut,         // cat + l*32, row stride 128
    int n)
{
    __shared__ u16 xs[64 * 104];      // A tile [64 nodes][96 kk] (+8 pad)
    __shared__ u16 bt[32 * 104];      // B^T tile
    __shared__ u32 cw[8];
    const int t = threadIdx.x;

    if (t < 8) cw[t] = f2bf(comp[2 * t]) | (f2bf(comp[2 * t + 1]) << 16);

    // stage B^T: bt[o][kk]: kk<32 -> B0[kk,o]; 32..63 -> B1; 64..95 -> Wself
    for (int f = t; f < 32 * 12; f += 256) {
        int c8 = f >> 5, o = f & 31;
        u32 pk[4];
#pragma unroll
        for (int e = 0; e < 4; ++e) {
            int k0 = c8 * 8 + 2 * e, k1v = k0 + 1;
            float v0 = (k0 < 64) ? basis[(size_t)(k0 >> 5) * 1024 + (k0 & 31) * 32 + o]
                                 : wself[(size_t)(k0 - 64) * 32 + o];
            float v1 = (k1v < 64) ? basis[(size_t)(k1v >> 5) * 1024 + (k1v & 31) * 32 + o]
                                  : wself[(size_t)(k1v - 64) * 32 + o];
            pk[e] = f2bf(v0) | (f2bf(v1) << 16);
        }
        *(uint4*)(bt + o * 104 + c8 * 8) = *(uint4*)pk;
    }

    // ---- phase 1: aggregate (4 lanes/node, 8 dims each) ----
    const int node0 = blockIdx.x * 64;
    const int nloc = t >> 2;
    const int i = t & 3;
    const int node = node0 + nloc;

    // stage own h chunk (kk 64..95): thread (nloc,i) covers 8 dims
    {
        uint4 v = make_uint4(0u, 0u, 0u, 0u);
        if (node < n) v = *(const uint4*)(catPrev + (size_t)node * 128 + i * 8);
        *(uint4*)(xs + nloc * 104 + (8 + i) * 8) = v;
    }
    __syncthreads();   // cw visible to all; xs h-chunks in place

    float y0[8], y1[8];
#pragma unroll
    for (int m = 0; m < 8; ++m) { y0[m] = 0.f; y1[m] = 0.f; }
    if (node < n) {
        int k = rowptr[node];
        const int k1 = rowptr[node + 1];
        const unsigned gbase = (unsigned)i * 16u;
        while (k + 8 <= k1) { aggy_block<8>(catPrev, epack, k, i, gbase, cw, y0, y1); k += 8; }
        const int r = k1 - k;
        if (r & 4) { aggy_block<4>(catPrev, epack, k, i, gbase, cw, y0, y1); k += 4; }
        if (r & 2) { aggy_block<2>(catPrev, epack, k, i, gbase, cw, y0, y1); k += 2; }
        if (r & 1) { aggy_block<1>(catPrev, epack, k, i, gbase, cw, y0, y1); }
    }
    // y0 -> kk i*8..i*8+7 (chunk i); y1 -> kk 32+i*8.. (chunk 4+i)
    {
        uint4 o0, o1;
        o0.x = f2bf(y0[0]) | (f2bf(y0[1]) << 16);
        o0.y = f2bf(y0[2]) | (f2bf(y0[3]) << 16);
        o0.z = f2bf(y0[4]) | (f2bf(y0[5]) << 16);
        o0.w = f2bf(y0[6]) | (f2bf(y0[7]) << 16);
        o1.x = f2bf(y1[0]) | (f2bf(y1[1]) << 16);
        o1.y = f2bf(y1[2]) | (f2bf(y1[3]) << 16);
        o1.z = f2bf(y1[4]) | (f2bf(y1[5]) << 16);
        o1.w = f2bf(y1[6]) | (f2bf(y1[7]) << 16);
        *(uint4*)(xs + nloc * 104 + i * 8) = o0;
        *(uint4*)(xs + nloc * 104 + (4 + i) * 8) = o1;
    }
    __syncthreads();

    // ---- phase 2: MFMA [64x96] @ [96x32] ----
    const int w = t >> 6;
    const int l = t & 63;
    const int lr = l & 15;
    const int lg = l >> 4;

    f32x4 c0 = (f32x4){0.f, 0.f, 0.f, 0.f};
    f32x4 c1 = (f32x4){0.f, 0.f, 0.f, 0.f};
#pragma unroll
    for (int ks = 0; ks < 3; ++ks) {
        const int ch = ks * 4 + lg;           // chunk 0..11
        bf16x8 a  = *(const bf16x8*)(xs + (w * 16 + lr) * 104 + ch * 8);
        bf16x8 b0 = *(const bf16x8*)(bt + lr * 104 + ch * 8);
        bf16x8 b1 = *(const bf16x8*)(bt + (16 + lr) * 104 + ch * 8);
        c0 = __builtin_amdgcn_mfma_f32_16x16x32_bf16(a, b0, c0, 0, 0, 0);
        c1 = __builtin_amdgcn_mfma_f32_16x16x32_bf16(a, b1, c1, 0, 0, 0);
    }

    const float bia0 = bias[lr];
    const float bia1 = bias[16 + lr];
#pragma unroll
    for (int r = 0; r < 4; ++r) {
        int nodeW = node0 + w * 16 + lg * 4 + r;
        if (nodeW < n) {
            catOut[(size_t)nodeW * 128 + lr]      = (u16)f2bf(fast_tanh(c0[r] + bia0));
            catOut[(size_t)nodeW * 128 + 16 + lr] = (u16)f2bf(fast_tanh(c1[r] + bia1));
        }
    }
}

// ---- head: one wave per pair, 256-dim dot (bf16 cat) + sigmoid ----
__global__ void k_head(const u16* __restrict__ cat, const int* __restrict__ uidx,
                       const int* __restrict__ iidx, const float* __restrict__ w,
                       const float* __restrict__ b, float* __restrict__ out, int B) {
    int p = blockIdx.x;
    if (p >= B) return;
    int lane = threadIdx.x;  // 0..63
    const u16* cu = cat + (size_t)uidx[p] * 128;
    const u16* ci = cat + (size_t)iidx[p] * 128;
    float s = 0.f;
    s = fmaf(bf2f(cu[lane]), w[lane], s);
    s = fmaf(bf2f(cu[lane + 64]), w[lane + 64], s);
    s = fmaf(bf2f(ci[lane]), w[lane + 128], s);
    s = fmaf(bf2f(ci[lane + 64]), w[lane + 192], s);
    for (int d = 32; d > 0; d >>= 1) s += __shfl_down(s, d, 64);
    if (lane == 0) out[p] = 1.f / (1.f + expf(-(s + b[0])));
}

extern "C" void kernel_launch(void* const* d_in, const int* in_sizes, int n_in,
                              void* d_out, int out_size, void* d_ws, size_t ws_size,
                              hipStream_t stream) {
    const float* x      = (const float*)d_in[0];
    const int*   src    = (const int*)d_in[1];
    const int*   dst    = (const int*)d_in[2];
    const int*   etype  = (const int*)d_in[3];
    const int*   uidx   = (const int*)d_in[4];
    const int*   iidx   = (const int*)d_in[5];
    const float* lin1_w = (const float*)d_in[22];
    const float* lin1_b = (const float*)d_in[23];

    const int N = in_sizes[0] / 64;
    const int E = in_sizes[1];
    const int B = in_sizes[4];
    const int NBUK = (N + BUK_W - 1) >> BUK_SH;

    // workspace carve-out (256B aligned)
    char* p = (char*)d_ws;
    auto alloc = [&](size_t bytes) -> void* {
        void* r = (void*)p;
        p += (bytes + 255) & ~(size_t)255;
        return r;
    };
    u32*   hb2     = (u32*)alloc((size_t)N * 32 * sizeof(u32));
    float* self0   = (float*)alloc((size_t)N * 32 * sizeof(float));
    u16*   cat     = (u16*)alloc((size_t)N * 128 * sizeof(u16));
    int*   rowptr  = (int*)alloc((size_t)(N + 1) * sizeof(int));
    u32*   epack   = (u32*)alloc((size_t)E * sizeof(u32));
    u32*   binned  = (u32*)alloc((size_t)E * sizeof(u32));
    int*   gBukCnt = (int*)alloc(1024 * sizeof(int));
    int*   gBukCur = (int*)alloc(1024 * sizeof(int));  // adjacent to gBukCnt
    int*   bukOff  = (int*)alloc(1025 * sizeof(int));

    // ---- CSR build (bucket pipeline) ----
    k_zero<<<8, 256, 0, stream>>>(gBukCnt, 2048);   // gBukCnt + gBukCur
    int ebGrid = (E + 2047) / 2048;
    k_buk_count<<<ebGrid, 256, 0, stream>>>(dst, gBukCnt, E);
    k_buk_scan<<<1, 1024, 0, stream>>>(gBukCnt, bukOff, NBUK);
    k_binscatter<<<ebGrid, 256, 0, stream>>>(src, dst, etype, bukOff, gBukCur,
                                             binned, E, NBUK);
    k_bucket_finalize<<<NBUK, 256, 0, stream>>>(binned, bukOff, rowptr, epack, N, E);

    const int tr_grid = (N + 63) / 64;

    // ---- layer 0: transform -> aggregate (x is 64-dim) ----
    k_transform3<64><<<tr_grid, 256, 0, stream>>>(
        x, 64, (const float*)d_in[6], (const float*)d_in[8], (const float*)d_in[9],
        hb2, self0, N);
    k_aggregate0<<<(N * 8 + 255) / 256, 256, 0, stream>>>(
        hb2, epack, rowptr, (const float*)d_in[7], self0, cat, N);

    // ---- layers 1-3: fused aggregate+transform ----
    for (int l = 1; l < 4; ++l) {
        k_layer_y<<<tr_grid, 256, 0, stream>>>(
            cat + (size_t)(l - 1) * 32, epack, rowptr,
            (const float*)d_in[7 + l * 4], (const float*)d_in[6 + l * 4],
            (const float*)d_in[8 + l * 4], (const float*)d_in[9 + l * 4],
            cat + (size_t)l * 32, N);
    }

    // ---- head ----
    k_head<<<B, 64, 0, stream>>>(cat, uidx, iidx, lin1_w, lin1_b, (float*)d_out, B);
}

// Round 17
// 400.753 us; speedup vs baseline: 1.0064x; 1.0058x over previous
//
#include <hip/hip_runtime.h>
#include <hip/hip_bf16.h>

// ---------------------------------------------------------------------------
// RGCN (basis decomposition) x4 layers + pair-scoring head.
//
// CSR build (bucket pipeline); memset via k_zero.
//
// Layer 0 (x is 64-dim, f32 input):
//   k_transform3<64> : MFMA GEMM -> hb2 (bf16x2 msg pairs) + self0 (f32[N,32])
//   k_aggregate0     : gather hb2 128B rows, acc += self0, tanh -> cat bf16
//
// Layers 1-3 (algebra swap + FUSED — R12 config, best measured; R14 showed
// split was 20us slower, fills were profiling artifacts):
//   k_layer_y : phase 1 aggregates y_b = sum_e comp[et,b]*h[src] (64B bf16
//               gathers) into registers -> bf16 into LDS A-tile [64x96];
//               phase 2 MFMA [A](K=96) @ [B0;B1;Wself] + bias, tanh -> cat.
//               LDS tiles use 104-u16 (208B) row stride: 20,000B total ->
//               8 blocks/CU (32 waves, was 6/24 at pow2+XOR) for the
//               latency-bound gather phase. __launch_bounds__(256,8).
//
// cat: bf16 [N,128] holds all 4 layer states. k_head: wave/pair dot+sigmoid.
// ---------------------------------------------------------------------------

#define SRC_MASK 0x3FFFFu
#define BUK_SH 9
#define BUK_W 512

typedef __attribute__((ext_vector_type(8))) short bf16x8;
typedef __attribute__((ext_vector_type(4))) float f32x4;
typedef unsigned short u16;
typedef unsigned int u32;

__device__ inline u32 f2bf(float f) {
    u32 u = __float_as_uint(f);
    return (u + 0x7FFFu + ((u >> 16) & 1u)) >> 16;
}
__device__ inline float bf2f(u32 lo16) { return __uint_as_float(lo16 << 16); }

__device__ inline float fast_tanh(float x) {
    float xc = fminf(fmaxf(x, -15.f), 15.f);
    float e = __expf(2.f * xc);
    return (e - 1.f) * __builtin_amdgcn_rcpf(e + 1.f);
}

__global__ void k_zero(int* __restrict__ p, int n) {
    int i = blockIdx.x * 256 + threadIdx.x;
    if (i < n) p[i] = 0;
}

// Exclusive scan in place of a[0..M), M%4==0, M/4 <= 256. 256-thread block.
__device__ inline void block_exscan(int* a, int M, int* wsum /*shared int[4]*/) {
    const int t = threadIdx.x;
    const int q = M >> 2;
    int s0 = 0, s1 = 0, s2 = 0, s3 = 0, s = 0;
    if (t < q) {
        s0 = a[4 * t]; s1 = a[4 * t + 1]; s2 = a[4 * t + 2]; s3 = a[4 * t + 3];
        s = s0 + s1 + s2 + s3;
    }
    int lane = t & 63, wid = t >> 6;
    int val = s;
    for (int d = 1; d < 64; d <<= 1) {
        int u = __shfl_up(val, d, 64);
        if (lane >= d) val += u;
    }
    if (lane == 63) wsum[wid] = val;
    __syncthreads();
    int woff = 0;
    for (int w = 0; w < wid; ++w) woff += wsum[w];
    val += woff;              // inclusive over block
    int base = val - s;       // exclusive base for this thread's 4 elems
    __syncthreads();
    if (t < q) {
        a[4 * t]     = base;
        a[4 * t + 1] = base + s0;
        a[4 * t + 2] = base + s0 + s1;
        a[4 * t + 3] = base + s0 + s1 + s2;
    }
    __syncthreads();
}

// ---- A: bucket histogram ----
__global__ __launch_bounds__(256) void k_buk_count(const int* __restrict__ dst,
                                                   int* __restrict__ gBukCnt, int E) {
    __shared__ int hist[1024];
    const int t = threadIdx.x;
    for (int f = t; f < 1024; f += 256) hist[f] = 0;
    __syncthreads();
    int e0 = blockIdx.x * 2048;
    for (int k = 0; k < 8; ++k) {
        int e = e0 + k * 256 + t;
        if (e < E) atomicAdd(&hist[dst[e] >> BUK_SH], 1);
    }
    __syncthreads();
    for (int f = t; f < 1024; f += 256) {
        int c = hist[f];
        if (c) atomicAdd(&gBukCnt[f], c);
    }
}

// ---- A2: scan bucket counts (1 block, 1024 threads; nb <= 1024) ----
__global__ void k_buk_scan(const int* __restrict__ gBukCnt, int* __restrict__ bukOff,
                           int nb) {
    __shared__ int lds[1024];
    int tid = threadIdx.x;
    int v = (tid < nb) ? gBukCnt[tid] : 0;
    lds[tid] = v;
    __syncthreads();
    for (int d = 1; d < 1024; d <<= 1) {
        int u = (tid >= d) ? lds[tid - d] : 0;
        __syncthreads();
        lds[tid] += u;
        __syncthreads();
    }
    if (tid < nb) bukOff[tid] = lds[tid] - v;       // exclusive
    if (tid == nb - 1) bukOff[nb] = lds[tid];       // total = E
}

// ---- B: block counting-sort by bucket + contiguous segment writeout ----
__global__ __launch_bounds__(256) void k_binscatter(
    const int* __restrict__ src, const int* __restrict__ dst,
    const int* __restrict__ etype, const int* __restrict__ bukOff,
    int* __restrict__ gBukCur, unsigned int* __restrict__ binned,
    int E, int NBUK)
{
    __shared__ int hist[1024];
    __shared__ int offs[1024];
    __shared__ int cur[1024];
    __shared__ int gb[1024];
    __shared__ int wsum[4];
    __shared__ unsigned int stage[2048];
    __shared__ unsigned short stageB[2048];   // bucket of each staged position
    const int t = threadIdx.x;
    for (int f = t; f < 1024; f += 256) { hist[f] = 0; cur[f] = 0; }
    __syncthreads();

    const int e0 = blockIdx.x * 2048;
    const int cntTot = min(2048, E - e0);
    unsigned int pk[8];
    int bk[8];
#pragma unroll
    for (int k = 0; k < 8; ++k) {
        int e = e0 + k * 256 + t;
        if (e < E) {
            int d = dst[e];
            bk[k] = d >> BUK_SH;
            pk[k] = (unsigned int)src[e]
                  | ((unsigned int)etype[e] << 29)
                  | ((unsigned int)(d & (BUK_W - 1)) << 20);
            atomicAdd(&hist[bk[k]], 1);
        } else bk[k] = -1;
    }
    __syncthreads();
    for (int f = t; f < 1024; f += 256) offs[f] = hist[f];
    __syncthreads();
    block_exscan(offs, 1024, wsum);
#pragma unroll
    for (int k = 0; k < 8; ++k) {
        if (bk[k] >= 0) {
            int pos = offs[bk[k]] + atomicAdd(&cur[bk[k]], 1);
            stage[pos] = pk[k];
            stageB[pos] = (unsigned short)bk[k];
        }
    }
    // reserve global space per bucket (one atomic per non-empty bucket)
    for (int f = t; f < NBUK; f += 256) {
        int c = hist[f];
        if (c > 0) gb[f] = bukOff[f] + atomicAdd(&gBukCur[f], c);
    }
    __syncthreads();
    // contiguous per-bucket segments
    for (int k = t; k < cntTot; k += 256) {
        int b = stageB[k];
        binned[(size_t)gb[b] + (size_t)(k - offs[b])] = stage[k];
    }
}

// ---- C: per-bucket finalize: rowptr + epack (all writes in 16KB window) ----
__global__ __launch_bounds__(256) void k_bucket_finalize(
    const unsigned int* __restrict__ binned, const int* __restrict__ bukOff,
    int* __restrict__ rowptr, unsigned int* __restrict__ epack, int N, int E)
{
    __shared__ int nhist[512];
    __shared__ int ncur[512];
    __shared__ int wsum[4];
    const int t = threadIdx.x;
    const int b = blockIdx.x;
    for (int f = t; f < 512; f += 256) { nhist[f] = 0; ncur[f] = 0; }
    __syncthreads();
    const int k0 = bukOff[b], k1 = bukOff[b + 1];
    for (int k = k0 + t; k < k1; k += 256)
        atomicAdd(&nhist[(binned[k] >> 20) & (BUK_W - 1)], 1);
    __syncthreads();
    block_exscan(nhist, 512, wsum);
    for (int f = t; f < 512; f += 256) {
        int node = (b << BUK_SH) + f;
        if (node < N) rowptr[node] = k0 + nhist[f];
    }
    if (b == 0 && t == 0) rowptr[N] = E;
    for (int k = k0 + t; k < k1; k += 256) {
        unsigned int v = binned[k];
        int dl = (v >> 20) & (BUK_W - 1);
        int pos = k0 + nhist[dl] + atomicAdd(&ncur[dl], 1);
        epack[pos] = v & 0xE003FFFFu;   // et[31:29] | src[17:0]
    }
}

// ---- MFMA transform, layer 0 ----
template<int DI>
__global__ __launch_bounds__(256) void k_transform3(
    const float* __restrict__ xin, int in_stride,
    const float* __restrict__ basis, const float* __restrict__ wself,
    const float* __restrict__ bias,
    u32* __restrict__ hb2, float* __restrict__ self0, int n)
{
    constexpr int ROWB = DI * 2;
    constexpr int SMASK = (ROWB / 16) - 1;
    constexpr int C4 = DI / 4;
    __shared__ u16 xs[64 * DI];
    __shared__ u16 bt[96 * DI];
    const int t = threadIdx.x;

    auto swz = [](int row, int byteInRow) -> int {
        int slot = (byteInRow >> 4) ^ ((row ^ (row >> 2)) & SMASK);
        return row * ROWB + (slot << 4) + (byteInRow & 15);
    };

    for (int f = t; f < 96 * C4; f += 256) {
        int k4 = f / 96;
        int o  = f - k4 * 96;
        const float* sp = (o < 64) ? (basis + (size_t)(o >> 5) * DI * 32 + (o & 31))
                                   : (wself + (o - 64));
        int k = 4 * k4;
        ushort4 pv;
        pv.x = (u16)f2bf(sp[(size_t)(k + 0) * 32]);
        pv.y = (u16)f2bf(sp[(size_t)(k + 1) * 32]);
        pv.z = (u16)f2bf(sp[(size_t)(k + 2) * 32]);
        pv.w = (u16)f2bf(sp[(size_t)(k + 3) * 32]);
        *(ushort4*)((char*)bt + swz(o, k * 2)) = pv;
    }

    const int node0 = blockIdx.x * 64;
    for (int f = t; f < 64 * C4; f += 256) {
        int nloc = f / C4, k4 = f - nloc * C4;
        int node = node0 + nloc;
        float4 v = make_float4(0.f, 0.f, 0.f, 0.f);
        if (node < n) v = *(const float4*)(xin + (size_t)node * in_stride + 4 * k4);
        ushort4 pv;
        pv.x = (u16)f2bf(v.x);
        pv.y = (u16)f2bf(v.y);
        pv.z = (u16)f2bf(v.z);
        pv.w = (u16)f2bf(v.w);
        *(ushort4*)((char*)xs + swz(nloc, 8 * k4)) = pv;
    }
    __syncthreads();

    const int w = t >> 6;
    const int l = t & 63;
    const int lr = l & 15;
    const int lg = l >> 4;

    f32x4 c[6];
#pragma unroll
    for (int i = 0; i < 6; ++i) c[i] = (f32x4){0.f, 0.f, 0.f, 0.f};

#pragma unroll
    for (int ks = 0; ks < DI / 32; ++ks) {
        const int kb = ks * 64 + lg * 16;
        bf16x8 a = *(const bf16x8*)((char*)xs + swz(w * 16 + lr, kb));
#pragma unroll
        for (int tt = 0; tt < 6; ++tt) {
            bf16x8 b = *(const bf16x8*)((char*)bt + swz(tt * 16 + lr, kb));
            c[tt] = __builtin_amdgcn_mfma_f32_16x16x32_bf16(a, b, c[tt], 0, 0, 0);
        }
    }

    const float bia0 = bias[lr];
    const float bia1 = bias[16 + lr];
#pragma unroll
    for (int r = 0; r < 4; ++r) {
        int node = node0 + w * 16 + lg * 4 + r;
        if (node < n) {
            hb2[(size_t)node * 32 + lr]      = f2bf(c[0][r]) | (f2bf(c[2][r]) << 16);
            hb2[(size_t)node * 32 + 16 + lr] = f2bf(c[1][r]) | (f2bf(c[3][r]) << 16);
            self0[(size_t)node * 32 + lr]      = c[4][r] + bia0;
            self0[(size_t)node * 32 + 16 + lr] = c[5][r] + bia1;
        }
    }
}

// ---- layer-0 aggregate: gather hb2 128B rows; epack shared via __shfl ----
template<int W>
__device__ __forceinline__ void agg0_block(
    const u32* __restrict__ hb2, const u32* __restrict__ epack,
    int k, int oj, unsigned gbase, const u32* cw, float4& acc)
{
    int pa;
    if (W == 8)      pa = (int)epack[k + oj];
    else if (W == 4) pa = (int)epack[k + (oj & 3)];
    else if (W == 2) pa = (int)epack[k + (oj & 1)];
    else             pa = (int)epack[k];
    u32 pp[W];
    uint4 hh[W];
#pragma unroll
    for (int j = 0; j < W; ++j) {
        pp[j] = (W > 1) ? (u32)__shfl(pa, j, 8) : (u32)pa;
        unsigned boff = (pp[j] & SRC_MASK) * 128u + gbase;
        hh[j] = *(const uint4*)((const char*)hb2 + boff);
    }
#pragma unroll
    for (int j = 0; j < W; ++j) {
        u32 w = cw[pp[j] >> 29];
        float w0 = __uint_as_float(w << 16);
        float w1 = __uint_as_float(w & 0xFFFF0000u);
        acc.x = fmaf(w0, __uint_as_float(hh[j].x << 16), acc.x);
        acc.x = fmaf(w1, __uint_as_float(hh[j].x & 0xFFFF0000u), acc.x);
        acc.y = fmaf(w0, __uint_as_float(hh[j].y << 16), acc.y);
        acc.y = fmaf(w1, __uint_as_float(hh[j].y & 0xFFFF0000u), acc.y);
        acc.z = fmaf(w0, __uint_as_float(hh[j].z << 16), acc.z);
        acc.z = fmaf(w1, __uint_as_float(hh[j].z & 0xFFFF0000u), acc.z);
        acc.w = fmaf(w0, __uint_as_float(hh[j].w << 16), acc.w);
        acc.w = fmaf(w1, __uint_as_float(hh[j].w & 0xFFFF0000u), acc.w);
    }
}

__global__ __launch_bounds__(256) void k_aggregate0(
    const u32* __restrict__ hb2,
    const u32* __restrict__ epack,
    const int* __restrict__ rowptr,
    const float* __restrict__ comp,   // [8,2]
    const float* __restrict__ self0,  // [N,32] f32
    u16* __restrict__ cat0,           // cat cols 0..31 (row stride 128 u16)
    int n)
{
    __shared__ u32 cw[8];
    if (threadIdx.x < 8)
        cw[threadIdx.x] = f2bf(comp[threadIdx.x * 2 + 0])
                        | (f2bf(comp[threadIdx.x * 2 + 1]) << 16);
    __syncthreads();
    int t = blockIdx.x * 256 + threadIdx.x;
    int node = t >> 3;
    int oj = t & 7;
    if (node >= n) return;
    float4 acc = *(const float4*)(self0 + (size_t)node * 32 + 4 * oj);
    int k = rowptr[node];
    const int k1 = rowptr[node + 1];
    const unsigned gbase = (unsigned)oj * 16u;

    while (k + 8 <= k1) { agg0_block<8>(hb2, epack, k, oj, gbase, cw, acc); k += 8; }
    const int r = k1 - k;
    if (r & 4) { agg0_block<4>(hb2, epack, k, oj, gbase, cw, acc); k += 4; }
    if (r & 2) { agg0_block<2>(hb2, epack, k, oj, gbase, cw, acc); k += 2; }
    if (r & 1) { agg0_block<1>(hb2, epack, k, oj, gbase, cw, acc); }

    ushort4 o;
    o.x = (u16)f2bf(fast_tanh(acc.x));
    o.y = (u16)f2bf(fast_tanh(acc.y));
    o.z = (u16)f2bf(fast_tanh(acc.z));
    o.w = (u16)f2bf(fast_tanh(acc.w));
    *(ushort4*)(cat0 + (size_t)node * 128 + 4 * oj) = o;
}

// ---- layers 1-3 FUSED: aggregate y (64B gathers) -> LDS -> MFMA -> tanh ----
template<int W>
__device__ __forceinline__ void aggy_block(
    const u16* __restrict__ catPrev, const u32* __restrict__ epack,
    int k, int i, unsigned gbase, const u32* cw, float* y0, float* y1)
{
    int pa, pb = 0;
    if (W == 8)      { pa = (int)epack[k + i]; pb = (int)epack[k + 4 + i]; }
    else if (W == 4)   pa = (int)epack[k + i];
    else if (W == 2)   pa = (int)epack[k + (i & 1)];
    else               pa = (int)epack[k];
    u32 pp[W];
    uint4 hh[W];
#pragma unroll
    for (int j = 0; j < W; ++j) {
        int v;
        if (W == 8)      v = (j < 4) ? __shfl(pa, j, 4) : __shfl(pb, j - 4, 4);
        else if (W > 1)  v = __shfl(pa, j, 4);
        else             v = pa;
        pp[j] = (u32)v;
        unsigned boff = (pp[j] & SRC_MASK) * 256u + gbase;
        hh[j] = *(const uint4*)((const char*)catPrev + boff);
    }
#pragma unroll
    for (int j = 0; j < W; ++j) {
        u32 w = cw[pp[j] >> 29];
        float w0 = __uint_as_float(w << 16);
        float w1 = __uint_as_float(w & 0xFFFF0000u);
        const u32* hp = (const u32*)&hh[j];
#pragma unroll
        for (int m = 0; m < 4; ++m) {
            u32 pair = hp[m];
            float ha = __uint_as_float(pair << 16);
            float hb = __uint_as_float(pair & 0xFFFF0000u);
            y0[2 * m]     = fmaf(w0, ha, y0[2 * m]);
            y1[2 * m]     = fmaf(w1, ha, y1[2 * m]);
            y0[2 * m + 1] = fmaf(w0, hb, y0[2 * m + 1]);
            y1[2 * m + 1] = fmaf(w1, hb, y1[2 * m + 1]);
        }
    }
}

// LDS row stride = 104 u16 (208B = 13x16B slots). 96 u16 content + 8 pad.
// Odd stride rotates row-start banks (20*r mod 32, period 8) -> <=2-way
// conflicts on staging/y-writes; ~8-way only on the 9 MFMA b128 reads
// (negligible vs gather phase). Total LDS 20,000B -> 8 blocks/CU (32 waves).
__global__ __launch_bounds__(256, 8) void k_layer_y(
    const u16* __restrict__ catPrev,  // cat + (l-1)*32, row stride 128 u16
    const u32* __restrict__ epack,
    const int* __restrict__ rowptr,
    const float* __restrict__ comp,   // [8,2]
    const float* __restrict__ basis,  // [2,32,32]
    const float* __restrict__ wself,  // [32,32]
    const float* __restrict__ bias,   // [32]
    u16* __restrict__ catOut,         // cat + l*32, row stride 128
    int n)
{
    __shared__ u16 xs[64 * 104];      // A tile [64 nodes][96 kk] (+8 pad)
    __shared__ u16 bt[32 * 104];      // B^T tile
    __shared__ u32 cw[8];
    const int t = threadIdx.x;

    if (t < 8) cw[t] = f2bf(comp[2 * t]) | (f2bf(comp[2 * t + 1]) << 16);

    // stage B^T: bt[o][kk]: kk<32 -> B0[kk,o]; 32..63 -> B1; 64..95 -> Wself
    for (int f = t; f < 32 * 12; f += 256) {
        int c8 = f >> 5, o = f & 31;
        u32 pk[4];
#pragma unroll
        for (int e = 0; e < 4; ++e) {
            int k0 = c8 * 8 + 2 * e, k1v = k0 + 1;
            float v0 = (k0 < 64) ? basis[(size_t)(k0 >> 5) * 1024 + (k0 & 31) * 32 + o]
                                 : wself[(size_t)(k0 - 64) * 32 + o];
            float v1 = (k1v < 64) ? basis[(size_t)(k1v >> 5) * 1024 + (k1v & 31) * 32 + o]
                                  : wself[(size_t)(k1v - 64) * 32 + o];
            pk[e] = f2bf(v0) | (f2bf(v1) << 16);
        }
        *(uint4*)(bt + o * 104 + c8 * 8) = *(uint4*)pk;
    }

    // ---- phase 1: aggregate (4 lanes/node, 8 dims each) ----
    const int node0 = blockIdx.x * 64;
    const int nloc = t >> 2;
    const int i = t & 3;
    const int node = node0 + nloc;

    // stage own h chunk (kk 64..95): thread (nloc,i) covers 8 dims
    {
        uint4 v = make_uint4(0u, 0u, 0u, 0u);
        if (node < n) v = *(const uint4*)(catPrev + (size_t)node * 128 + i * 8);
        *(uint4*)(xs + nloc * 104 + (8 + i) * 8) = v;
    }
    __syncthreads();   // cw visible to all; xs h-chunks in place

    float y0[8], y1[8];
#pragma unroll
    for (int m = 0; m < 8; ++m) { y0[m] = 0.f; y1[m] = 0.f; }
    if (node < n) {
        int k = rowptr[node];
        const int k1 = rowptr[node + 1];
        const unsigned gbase = (unsigned)i * 16u;
        while (k + 8 <= k1) { aggy_block<8>(catPrev, epack, k, i, gbase, cw, y0, y1); k += 8; }
        const int r = k1 - k;
        if (r & 4) { aggy_block<4>(catPrev, epack, k, i, gbase, cw, y0, y1); k += 4; }
        if (r & 2) { aggy_block<2>(catPrev, epack, k, i, gbase, cw, y0, y1); k += 2; }
        if (r & 1) { aggy_block<1>(catPrev, epack, k, i, gbase, cw, y0, y1); }
    }
    // y0 -> kk i*8..i*8+7 (chunk i); y1 -> kk 32+i*8.. (chunk 4+i)
    {
        uint4 o0, o1;
        o0.x = f2bf(y0[0]) | (f2bf(y0[1]) << 16);
        o0.y = f2bf(y0[2]) | (f2bf(y0[3]) << 16);
        o0.z = f2bf(y0[4]) | (f2bf(y0[5]) << 16);
        o0.w = f2bf(y0[6]) | (f2bf(y0[7]) << 16);
        o1.x = f2bf(y1[0]) | (f2bf(y1[1]) << 16);
        o1.y = f2bf(y1[2]) | (f2bf(y1[3]) << 16);
        o1.z = f2bf(y1[4]) | (f2bf(y1[5]) << 16);
        o1.w = f2bf(y1[6]) | (f2bf(y1[7]) << 16);
        *(uint4*)(xs + nloc * 104 + i * 8) = o0;
        *(uint4*)(xs + nloc * 104 + (4 + i) * 8) = o1;
    }
    __syncthreads();

    // ---- phase 2: MFMA [64x96] @ [96x32] ----
    const int w = t >> 6;
    const int l = t & 63;
    const int lr = l & 15;
    const int lg = l >> 4;

    f32x4 c0 = (f32x4){0.f, 0.f, 0.f, 0.f};
    f32x4 c1 = (f32x4){0.f, 0.f, 0.f, 0.f};
#pragma unroll
    for (int ks = 0; ks < 3; ++ks) {
        const int ch = ks * 4 + lg;           // chunk 0..11
        bf16x8 a  = *(const bf16x8*)(xs + (w * 16 + lr) * 104 + ch * 8);
        bf16x8 b0 = *(const bf16x8*)(bt + lr * 104 + ch * 8);
        bf16x8 b1 = *(const bf16x8*)(bt + (16 + lr) * 104 + ch * 8);
        c0 = __builtin_amdgcn_mfma_f32_16x16x32_bf16(a, b0, c0, 0, 0, 0);
        c1 = __builtin_amdgcn_mfma_f32_16x16x32_bf16(a, b1, c1, 0, 0, 0);
    }

    const float bia0 = bias[lr];
    const float bia1 = bias[16 + lr];
#pragma unroll
    for (int r = 0; r < 4; ++r) {
        int nodeW = node0 + w * 16 + lg * 4 + r;
        if (nodeW < n) {
            catOut[(size_t)nodeW * 128 + lr]      = (u16)f2bf(fast_tanh(c0[r] + bia0));
            catOut[(size_t)nodeW * 128 + 16 + lr] = (u16)f2bf(fast_tanh(c1[r] + bia1));
        }
    }
}

// ---- head: one wave per pair, 256-dim dot (bf16 cat) + sigmoid ----
__global__ void k_head(const u16* __restrict__ cat, const int* __restrict__ uidx,
                       const int* __restrict__ iidx, const float* __restrict__ w,
                       const float* __restrict__ b, float* __restrict__ out, int B) {
    int p = blockIdx.x;
    if (p >= B) return;
    int lane = threadIdx.x;  // 0..63
    const u16* cu = cat + (size_t)uidx[p] * 128;
    const u16* ci = cat + (size_t)iidx[p] * 128;
    float s = 0.f;
    s = fmaf(bf2f(cu[lane]), w[lane], s);
    s = fmaf(bf2f(cu[lane + 64]), w[lane + 64], s);
    s = fmaf(bf2f(ci[lane]), w[lane + 128], s);
    s = fmaf(bf2f(ci[lane + 64]), w[lane + 192], s);
    for (int d = 32; d > 0; d >>= 1) s += __shfl_down(s, d, 64);
    if (lane == 0) out[p] = 1.f / (1.f + expf(-(s + b[0])));
}

extern "C" void kernel_launch(void* const* d_in, const int* in_sizes, int n_in,
                              void* d_out, int out_size, void* d_ws, size_t ws_size,
                              hipStream_t stream) {
    const float* x      = (const float*)d_in[0];
    const int*   src    = (const int*)d_in[1];
    const int*   dst    = (const int*)d_in[2];
    const int*   etype  = (const int*)d_in[3];
    const int*   uidx   = (const int*)d_in[4];
    const int*   iidx   = (const int*)d_in[5];
    const float* lin1_w = (const float*)d_in[22];
    const float* lin1_b = (const float*)d_in[23];

    const int N = in_sizes[0] / 64;
    const int E = in_sizes[1];
    const int B = in_sizes[4];
    const int NBUK = (N + BUK_W - 1) >> BUK_SH;

    // workspace carve-out (256B aligned)
    char* p = (char*)d_ws;
    auto alloc = [&](size_t bytes) -> void* {
        void* r = (void*)p;
        p += (bytes + 255) & ~(size_t)255;
        return r;
    };
    u32*   hb2     = (u32*)alloc((size_t)N * 32 * sizeof(u32));
    float* self0   = (float*)alloc((size_t)N * 32 * sizeof(float));
    u16*   cat     = (u16*)alloc((size_t)N * 128 * sizeof(u16));
    int*   rowptr  = (int*)alloc((size_t)(N + 1) * sizeof(int));
    u32*   epack   = (u32*)alloc((size_t)E * sizeof(u32));
    u32*   binned  = (u32*)alloc((size_t)E * sizeof(u32));
    int*   gBukCnt = (int*)alloc(1024 * sizeof(int));
    int*   gBukCur = (int*)alloc(1024 * sizeof(int));  // adjacent to gBukCnt
    int*   bukOff  = (int*)alloc(1025 * sizeof(int));

    // ---- CSR build (bucket pipeline) ----
    k_zero<<<8, 256, 0, stream>>>(gBukCnt, 2048);   // gBukCnt + gBukCur
    int ebGrid = (E + 2047) / 2048;
    k_buk_count<<<ebGrid, 256, 0, stream>>>(dst, gBukCnt, E);
    k_buk_scan<<<1, 1024, 0, stream>>>(gBukCnt, bukOff, NBUK);
    k_binscatter<<<ebGrid, 256, 0, stream>>>(src, dst, etype, bukOff, gBukCur,
                                             binned, E, NBUK);
    k_bucket_finalize<<<NBUK, 256, 0, stream>>>(binned, bukOff, rowptr, epack, N, E);

    const int tr_grid = (N + 63) / 64;

    // ---- layer 0: transform -> aggregate (x is 64-dim) ----
    k_transform3<64><<<tr_grid, 256, 0, stream>>>(
        x, 64, (const float*)d_in[6], (const float*)d_in[8], (const float*)d_in[9],
        hb2, self0, N);
    k_aggregate0<<<(N * 8 + 255) / 256, 256, 0, stream>>>(
        hb2, epack, rowptr, (const float*)d_in[7], self0, cat, N);

    // ---- layers 1-3: fused aggregate+transform ----
    for (int l = 1; l < 4; ++l) {
        k_layer_y<<<tr_grid, 256, 0, stream>>>(
            cat + (size_t)(l - 1) * 32, epack, rowptr,
            (const float*)d_in[7 + l * 4], (const float*)d_in[6 + l * 4],
            (const float*)d_in[8 + l * 4], (const float*)d_in[9 + l * 4],
            cat + (size_t)l * 32, N);
    }

    // ---- head ----
    k_head<<<B, 64, 0, stream>>>(cat, uidx, iidx, lin1_w, lin1_b, (float*)d_out, B);
}

// Round 18
// 263.370 us; speedup vs baseline: 1.5314x; 1.5216x over previous
//
#include <hip/hip_runtime.h>
#include <hip/hip_bf16.h>

// ---------------------------------------------------------------------------
// RGCN (basis decomposition) x4 layers + pair-scoring head.
//
// CSR build (bucket pipeline); memset via k_zero.
//
// Layer 0 (x is 64-dim, f32 input):
//   k_transform3<64> : MFMA GEMM -> hb2 (bf16x2 msg pairs) + self0 (f32[N,32])
//   k_aggregate0     : gather hb2 128B rows, acc += self0, tanh -> cat bf16
//
// Layers 1-3 (algebra swap + FUSED — R12 config):
//   k_layer_y : phase 1 aggregates y_b = sum_e comp[et,b]*h[src] (64B bf16
//               gathers) into registers -> bf16 into LDS A-tile [64x96];
//               phase 2 MFMA [A](K=96) @ [B0;B1;Wself] + bias, tanh -> cat.
//               LDS 104-u16 row stride (20,000B -> 8 blocks/CU; R17 showed
//               occupancy 36.7->69%). NO min-waves launch bound: R17's
//               __launch_bounds__(256,8) forced VGPR 52->32 and spilled
//               (WRITE_SIZE 12.5->111MB, 100us). Plain (256) keeps ~52 VGPR
//               (<=64 still allows 8 waves/SIMD) with zero spill.
//
// cat: bf16 [N,128] holds all 4 layer states. k_head: wave/pair dot+sigmoid.
// ---------------------------------------------------------------------------

#define SRC_MASK 0x3FFFFu
#define BUK_SH 9
#define BUK_W 512

typedef __attribute__((ext_vector_type(8))) short bf16x8;
typedef __attribute__((ext_vector_type(4))) float f32x4;
typedef unsigned short u16;
typedef unsigned int u32;

__device__ inline u32 f2bf(float f) {
    u32 u = __float_as_uint(f);
    return (u + 0x7FFFu + ((u >> 16) & 1u)) >> 16;
}
__device__ inline float bf2f(u32 lo16) { return __uint_as_float(lo16 << 16); }

__device__ inline float fast_tanh(float x) {
    float xc = fminf(fmaxf(x, -15.f), 15.f);
    float e = __expf(2.f * xc);
    return (e - 1.f) * __builtin_amdgcn_rcpf(e + 1.f);
}

__global__ void k_zero(int* __restrict__ p, int n) {
    int i = blockIdx.x * 256 + threadIdx.x;
    if (i < n) p[i] = 0;
}

// Exclusive scan in place of a[0..M), M%4==0, M/4 <= 256. 256-thread block.
__device__ inline void block_exscan(int* a, int M, int* wsum /*shared int[4]*/) {
    const int t = threadIdx.x;
    const int q = M >> 2;
    int s0 = 0, s1 = 0, s2 = 0, s3 = 0, s = 0;
    if (t < q) {
        s0 = a[4 * t]; s1 = a[4 * t + 1]; s2 = a[4 * t + 2]; s3 = a[4 * t + 3];
        s = s0 + s1 + s2 + s3;
    }
    int lane = t & 63, wid = t >> 6;
    int val = s;
    for (int d = 1; d < 64; d <<= 1) {
        int u = __shfl_up(val, d, 64);
        if (lane >= d) val += u;
    }
    if (lane == 63) wsum[wid] = val;
    __syncthreads();
    int woff = 0;
    for (int w = 0; w < wid; ++w) woff += wsum[w];
    val += woff;              // inclusive over block
    int base = val - s;       // exclusive base for this thread's 4 elems
    __syncthreads();
    if (t < q) {
        a[4 * t]     = base;
        a[4 * t + 1] = base + s0;
        a[4 * t + 2] = base + s0 + s1;
        a[4 * t + 3] = base + s0 + s1 + s2;
    }
    __syncthreads();
}

// ---- A: bucket histogram ----
__global__ __launch_bounds__(256) void k_buk_count(const int* __restrict__ dst,
                                                   int* __restrict__ gBukCnt, int E) {
    __shared__ int hist[1024];
    const int t = threadIdx.x;
    for (int f = t; f < 1024; f += 256) hist[f] = 0;
    __syncthreads();
    int e0 = blockIdx.x * 2048;
    for (int k = 0; k < 8; ++k) {
        int e = e0 + k * 256 + t;
        if (e < E) atomicAdd(&hist[dst[e] >> BUK_SH], 1);
    }
    __syncthreads();
    for (int f = t; f < 1024; f += 256) {
        int c = hist[f];
        if (c) atomicAdd(&gBukCnt[f], c);
    }
}

// ---- A2: scan bucket counts (1 block, 1024 threads; nb <= 1024) ----
__global__ void k_buk_scan(const int* __restrict__ gBukCnt, int* __restrict__ bukOff,
                           int nb) {
    __shared__ int lds[1024];
    int tid = threadIdx.x;
    int v = (tid < nb) ? gBukCnt[tid] : 0;
    lds[tid] = v;
    __syncthreads();
    for (int d = 1; d < 1024; d <<= 1) {
        int u = (tid >= d) ? lds[tid - d] : 0;
        __syncthreads();
        lds[tid] += u;
        __syncthreads();
    }
    if (tid < nb) bukOff[tid] = lds[tid] - v;       // exclusive
    if (tid == nb - 1) bukOff[nb] = lds[tid];       // total = E
}

// ---- B: block counting-sort by bucket + contiguous segment writeout ----
__global__ __launch_bounds__(256) void k_binscatter(
    const int* __restrict__ src, const int* __restrict__ dst,
    const int* __restrict__ etype, const int* __restrict__ bukOff,
    int* __restrict__ gBukCur, unsigned int* __restrict__ binned,
    int E, int NBUK)
{
    __shared__ int hist[1024];
    __shared__ int offs[1024];
    __shared__ int cur[1024];
    __shared__ int gb[1024];
    __shared__ int wsum[4];
    __shared__ unsigned int stage[2048];
    __shared__ unsigned short stageB[2048];   // bucket of each staged position
    const int t = threadIdx.x;
    for (int f = t; f < 1024; f += 256) { hist[f] = 0; cur[f] = 0; }
    __syncthreads();

    const int e0 = blockIdx.x * 2048;
    const int cntTot = min(2048, E - e0);
    unsigned int pk[8];
    int bk[8];
#pragma unroll
    for (int k = 0; k < 8; ++k) {
        int e = e0 + k * 256 + t;
        if (e < E) {
            int d = dst[e];
            bk[k] = d >> BUK_SH;
            pk[k] = (unsigned int)src[e]
                  | ((unsigned int)etype[e] << 29)
                  | ((unsigned int)(d & (BUK_W - 1)) << 20);
            atomicAdd(&hist[bk[k]], 1);
        } else bk[k] = -1;
    }
    __syncthreads();
    for (int f = t; f < 1024; f += 256) offs[f] = hist[f];
    __syncthreads();
    block_exscan(offs, 1024, wsum);
#pragma unroll
    for (int k = 0; k < 8; ++k) {
        if (bk[k] >= 0) {
            int pos = offs[bk[k]] + atomicAdd(&cur[bk[k]], 1);
            stage[pos] = pk[k];
            stageB[pos] = (unsigned short)bk[k];
        }
    }
    // reserve global space per bucket (one atomic per non-empty bucket)
    for (int f = t; f < NBUK; f += 256) {
        int c = hist[f];
        if (c > 0) gb[f] = bukOff[f] + atomicAdd(&gBukCur[f], c);
    }
    __syncthreads();
    // contiguous per-bucket segments
    for (int k = t; k < cntTot; k += 256) {
        int b = stageB[k];
        binned[(size_t)gb[b] + (size_t)(k - offs[b])] = stage[k];
    }
}

// ---- C: per-bucket finalize: rowptr + epack (all writes in 16KB window) ----
__global__ __launch_bounds__(256) void k_bucket_finalize(
    const unsigned int* __restrict__ binned, const int* __restrict__ bukOff,
    int* __restrict__ rowptr, unsigned int* __restrict__ epack, int N, int E)
{
    __shared__ int nhist[512];
    __shared__ int ncur[512];
    __shared__ int wsum[4];
    const int t = threadIdx.x;
    const int b = blockIdx.x;
    for (int f = t; f < 512; f += 256) { nhist[f] = 0; ncur[f] = 0; }
    __syncthreads();
    const int k0 = bukOff[b], k1 = bukOff[b + 1];
    for (int k = k0 + t; k < k1; k += 256)
        atomicAdd(&nhist[(binned[k] >> 20) & (BUK_W - 1)], 1);
    __syncthreads();
    block_exscan(nhist, 512, wsum);
    for (int f = t; f < 512; f += 256) {
        int node = (b << BUK_SH) + f;
        if (node < N) rowptr[node] = k0 + nhist[f];
    }
    if (b == 0 && t == 0) rowptr[N] = E;
    for (int k = k0 + t; k < k1; k += 256) {
        unsigned int v = binned[k];
        int dl = (v >> 20) & (BUK_W - 1);
        int pos = k0 + nhist[dl] + atomicAdd(&ncur[dl], 1);
        epack[pos] = v & 0xE003FFFFu;   // et[31:29] | src[17:0]
    }
}

// ---- MFMA transform, layer 0 ----
template<int DI>
__global__ __launch_bounds__(256) void k_transform3(
    const float* __restrict__ xin, int in_stride,
    const float* __restrict__ basis, const float* __restrict__ wself,
    const float* __restrict__ bias,
    u32* __restrict__ hb2, float* __restrict__ self0, int n)
{
    constexpr int ROWB = DI * 2;
    constexpr int SMASK = (ROWB / 16) - 1;
    constexpr int C4 = DI / 4;
    __shared__ u16 xs[64 * DI];
    __shared__ u16 bt[96 * DI];
    const int t = threadIdx.x;

    auto swz = [](int row, int byteInRow) -> int {
        int slot = (byteInRow >> 4) ^ ((row ^ (row >> 2)) & SMASK);
        return row * ROWB + (slot << 4) + (byteInRow & 15);
    };

    for (int f = t; f < 96 * C4; f += 256) {
        int k4 = f / 96;
        int o  = f - k4 * 96;
        const float* sp = (o < 64) ? (basis + (size_t)(o >> 5) * DI * 32 + (o & 31))
                                   : (wself + (o - 64));
        int k = 4 * k4;
        ushort4 pv;
        pv.x = (u16)f2bf(sp[(size_t)(k + 0) * 32]);
        pv.y = (u16)f2bf(sp[(size_t)(k + 1) * 32]);
        pv.z = (u16)f2bf(sp[(size_t)(k + 2) * 32]);
        pv.w = (u16)f2bf(sp[(size_t)(k + 3) * 32]);
        *(ushort4*)((char*)bt + swz(o, k * 2)) = pv;
    }

    const int node0 = blockIdx.x * 64;
    for (int f = t; f < 64 * C4; f += 256) {
        int nloc = f / C4, k4 = f - nloc * C4;
        int node = node0 + nloc;
        float4 v = make_float4(0.f, 0.f, 0.f, 0.f);
        if (node < n) v = *(const float4*)(xin + (size_t)node * in_stride + 4 * k4);
        ushort4 pv;
        pv.x = (u16)f2bf(v.x);
        pv.y = (u16)f2bf(v.y);
        pv.z = (u16)f2bf(v.z);
        pv.w = (u16)f2bf(v.w);
        *(ushort4*)((char*)xs + swz(nloc, 8 * k4)) = pv;
    }
    __syncthreads();

    const int w = t >> 6;
    const int l = t & 63;
    const int lr = l & 15;
    const int lg = l >> 4;

    f32x4 c[6];
#pragma unroll
    for (int i = 0; i < 6; ++i) c[i] = (f32x4){0.f, 0.f, 0.f, 0.f};

#pragma unroll
    for (int ks = 0; ks < DI / 32; ++ks) {
        const int kb = ks * 64 + lg * 16;
        bf16x8 a = *(const bf16x8*)((char*)xs + swz(w * 16 + lr, kb));
#pragma unroll
        for (int tt = 0; tt < 6; ++tt) {
            bf16x8 b = *(const bf16x8*)((char*)bt + swz(tt * 16 + lr, kb));
            c[tt] = __builtin_amdgcn_mfma_f32_16x16x32_bf16(a, b, c[tt], 0, 0, 0);
        }
    }

    const float bia0 = bias[lr];
    const float bia1 = bias[16 + lr];
#pragma unroll
    for (int r = 0; r < 4; ++r) {
        int node = node0 + w * 16 + lg * 4 + r;
        if (node < n) {
            hb2[(size_t)node * 32 + lr]      = f2bf(c[0][r]) | (f2bf(c[2][r]) << 16);
            hb2[(size_t)node * 32 + 16 + lr] = f2bf(c[1][r]) | (f2bf(c[3][r]) << 16);
            self0[(size_t)node * 32 + lr]      = c[4][r] + bia0;
            self0[(size_t)node * 32 + 16 + lr] = c[5][r] + bia1;
        }
    }
}

// ---- layer-0 aggregate: gather hb2 128B rows; epack shared via __shfl ----
template<int W>
__device__ __forceinline__ void agg0_block(
    const u32* __restrict__ hb2, const u32* __restrict__ epack,
    int k, int oj, unsigned gbase, const u32* cw, float4& acc)
{
    int pa;
    if (W == 8)      pa = (int)epack[k + oj];
    else if (W == 4) pa = (int)epack[k + (oj & 3)];
    else if (W == 2) pa = (int)epack[k + (oj & 1)];
    else             pa = (int)epack[k];
    u32 pp[W];
    uint4 hh[W];
#pragma unroll
    for (int j = 0; j < W; ++j) {
        pp[j] = (W > 1) ? (u32)__shfl(pa, j, 8) : (u32)pa;
        unsigned boff = (pp[j] & SRC_MASK) * 128u + gbase;
        hh[j] = *(const uint4*)((const char*)hb2 + boff);
    }
#pragma unroll
    for (int j = 0; j < W; ++j) {
        u32 w = cw[pp[j] >> 29];
        float w0 = __uint_as_float(w << 16);
        float w1 = __uint_as_float(w & 0xFFFF0000u);
        acc.x = fmaf(w0, __uint_as_float(hh[j].x << 16), acc.x);
        acc.x = fmaf(w1, __uint_as_float(hh[j].x & 0xFFFF0000u), acc.x);
        acc.y = fmaf(w0, __uint_as_float(hh[j].y << 16), acc.y);
        acc.y = fmaf(w1, __uint_as_float(hh[j].y & 0xFFFF0000u), acc.y);
        acc.z = fmaf(w0, __uint_as_float(hh[j].z << 16), acc.z);
        acc.z = fmaf(w1, __uint_as_float(hh[j].z & 0xFFFF0000u), acc.z);
        acc.w = fmaf(w0, __uint_as_float(hh[j].w << 16), acc.w);
        acc.w = fmaf(w1, __uint_as_float(hh[j].w & 0xFFFF0000u), acc.w);
    }
}

__global__ __launch_bounds__(256) void k_aggregate0(
    const u32* __restrict__ hb2,
    const u32* __restrict__ epack,
    const int* __restrict__ rowptr,
    const float* __restrict__ comp,   // [8,2]
    const float* __restrict__ self0,  // [N,32] f32
    u16* __restrict__ cat0,           // cat cols 0..31 (row stride 128 u16)
    int n)
{
    __shared__ u32 cw[8];
    if (threadIdx.x < 8)
        cw[threadIdx.x] = f2bf(comp[threadIdx.x * 2 + 0])
                        | (f2bf(comp[threadIdx.x * 2 + 1]) << 16);
    __syncthreads();
    int t = blockIdx.x * 256 + threadIdx.x;
    int node = t >> 3;
    int oj = t & 7;
    if (node >= n) return;
    float4 acc = *(const float4*)(self0 + (size_t)node * 32 + 4 * oj);
    int k = rowptr[node];
    const int k1 = rowptr[node + 1];
    const unsigned gbase = (unsigned)oj * 16u;

    while (k + 8 <= k1) { agg0_block<8>(hb2, epack, k, oj, gbase, cw, acc); k += 8; }
    const int r = k1 - k;
    if (r & 4) { agg0_block<4>(hb2, epack, k, oj, gbase, cw, acc); k += 4; }
    if (r & 2) { agg0_block<2>(hb2, epack, k, oj, gbase, cw, acc); k += 2; }
    if (r & 1) { agg0_block<1>(hb2, epack, k, oj, gbase, cw, acc); }

    ushort4 o;
    o.x = (u16)f2bf(fast_tanh(acc.x));
    o.y = (u16)f2bf(fast_tanh(acc.y));
    o.z = (u16)f2bf(fast_tanh(acc.z));
    o.w = (u16)f2bf(fast_tanh(acc.w));
    *(ushort4*)(cat0 + (size_t)node * 128 + 4 * oj) = o;
}

// ---- layers 1-3 FUSED: aggregate y (64B gathers) -> LDS -> MFMA -> tanh ----
template<int W>
__device__ __forceinline__ void aggy_block(
    const u16* __restrict__ catPrev, const u32* __restrict__ epack,
    int k, int i, unsigned gbase, const u32* cw, float* y0, float* y1)
{
    int pa, pb = 0;
    if (W == 8)      { pa = (int)epack[k + i]; pb = (int)epack[k + 4 + i]; }
    else if (W == 4)   pa = (int)epack[k + i];
    else if (W == 2)   pa = (int)epack[k + (i & 1)];
    else               pa = (int)epack[k];
    u32 pp[W];
    uint4 hh[W];
#pragma unroll
    for (int j = 0; j < W; ++j) {
        int v;
        if (W == 8)      v = (j < 4) ? __shfl(pa, j, 4) : __shfl(pb, j - 4, 4);
        else if (W > 1)  v = __shfl(pa, j, 4);
        else             v = pa;
        pp[j] = (u32)v;
        unsigned boff = (pp[j] & SRC_MASK) * 256u + gbase;
        hh[j] = *(const uint4*)((const char*)catPrev + boff);
    }
#pragma unroll
    for (int j = 0; j < W; ++j) {
        u32 w = cw[pp[j] >> 29];
        float w0 = __uint_as_float(w << 16);
        float w1 = __uint_as_float(w & 0xFFFF0000u);
        const u32* hp = (const u32*)&hh[j];
#pragma unroll
        for (int m = 0; m < 4; ++m) {
            u32 pair = hp[m];
            float ha = __uint_as_float(pair << 16);
            float hb = __uint_as_float(pair & 0xFFFF0000u);
            y0[2 * m]     = fmaf(w0, ha, y0[2 * m]);
            y1[2 * m]     = fmaf(w1, ha, y1[2 * m]);
            y0[2 * m + 1] = fmaf(w0, hb, y0[2 * m + 1]);
            y1[2 * m + 1] = fmaf(w1, hb, y1[2 * m + 1]);
        }
    }
}

// LDS row stride = 104 u16 (208B). Total LDS 20,000B -> 8 blocks/CU when
// VGPR permits. NO min-waves bound (R17: forcing it spilled).
__global__ __launch_bounds__(256) void k_layer_y(
    const u16* __restrict__ catPrev,  // cat + (l-1)*32, row stride 128 u16
    const u32* __restrict__ epack,
    const int* __restrict__ rowptr,
    const float* __restrict__ comp,   // [8,2]
    const float* __restrict__ basis,  // [2,32,32]
    const float* __restrict__ wself,  // [32,32]
    const float* __restrict__ bias,   // [32]
    u16* __restrict__ catOut,         // cat + l*32, row stride 128
    int n)
{
    __shared__ u16 xs[64 * 104];      // A tile [64 nodes][96 kk] (+8 pad)
    __shared__ u16 bt[32 * 104];      // B^T tile
    __shared__ u32 cw[8];
    const int t = threadIdx.x;

    if (t < 8) cw[t] = f2bf(comp[2 * t]) | (f2bf(comp[2 * t + 1]) << 16);

    // stage B^T: bt[o][kk]: kk<32 -> B0[kk,o]; 32..63 -> B1; 64..95 -> Wself
    for (int f = t; f < 32 * 12; f += 256) {
        int c8 = f >> 5, o = f & 31;
        u32 pk[4];
#pragma unroll
        for (int e = 0; e < 4; ++e) {
            int k0 = c8 * 8 + 2 * e, k1v = k0 + 1;
            float v0 = (k0 < 64) ? basis[(size_t)(k0 >> 5) * 1024 + (k0 & 31) * 32 + o]
                                 : wself[(size_t)(k0 - 64) * 32 + o];
            float v1 = (k1v < 64) ? basis[(size_t)(k1v >> 5) * 1024 + (k1v & 31) * 32 + o]
                                  : wself[(size_t)(k1v - 64) * 32 + o];
            pk[e] = f2bf(v0) | (f2bf(v1) << 16);
        }
        *(uint4*)(bt + o * 104 + c8 * 8) = *(uint4*)pk;
    }

    // ---- phase 1: aggregate (4 lanes/node, 8 dims each) ----
    const int node0 = blockIdx.x * 64;
    const int nloc = t >> 2;
    const int i = t & 3;
    const int node = node0 + nloc;

    // stage own h chunk (kk 64..95): thread (nloc,i) covers 8 dims
    {
        uint4 v = make_uint4(0u, 0u, 0u, 0u);
        if (node < n) v = *(const uint4*)(catPrev + (size_t)node * 128 + i * 8);
        *(uint4*)(xs + nloc * 104 + (8 + i) * 8) = v;
    }
    __syncthreads();   // cw visible to all; xs h-chunks in place

    float y0[8], y1[8];
#pragma unroll
    for (int m = 0; m < 8; ++m) { y0[m] = 0.f; y1[m] = 0.f; }
    if (node < n) {
        int k = rowptr[node];
        const int k1 = rowptr[node + 1];
        const unsigned gbase = (unsigned)i * 16u;
        while (k + 8 <= k1) { aggy_block<8>(catPrev, epack, k, i, gbase, cw, y0, y1); k += 8; }
        const int r = k1 - k;
        if (r & 4) { aggy_block<4>(catPrev, epack, k, i, gbase, cw, y0, y1); k += 4; }
        if (r & 2) { aggy_block<2>(catPrev, epack, k, i, gbase, cw, y0, y1); k += 2; }
        if (r & 1) { aggy_block<1>(catPrev, epack, k, i, gbase, cw, y0, y1); }
    }
    // y0 -> kk i*8..i*8+7 (chunk i); y1 -> kk 32+i*8.. (chunk 4+i)
    {
        uint4 o0, o1;
        o0.x = f2bf(y0[0]) | (f2bf(y0[1]) << 16);
        o0.y = f2bf(y0[2]) | (f2bf(y0[3]) << 16);
        o0.z = f2bf(y0[4]) | (f2bf(y0[5]) << 16);
        o0.w = f2bf(y0[6]) | (f2bf(y0[7]) << 16);
        o1.x = f2bf(y1[0]) | (f2bf(y1[1]) << 16);
        o1.y = f2bf(y1[2]) | (f2bf(y1[3]) << 16);
        o1.z = f2bf(y1[4]) | (f2bf(y1[5]) << 16);
        o1.w = f2bf(y1[6]) | (f2bf(y1[7]) << 16);
        *(uint4*)(xs + nloc * 104 + i * 8) = o0;
        *(uint4*)(xs + nloc * 104 + (4 + i) * 8) = o1;
    }
    __syncthreads();

    // ---- phase 2: MFMA [64x96] @ [96x32] ----
    const int w = t >> 6;
    const int l = t & 63;
    const int lr = l & 15;
    const int lg = l >> 4;

    f32x4 c0 = (f32x4){0.f, 0.f, 0.f, 0.f};
    f32x4 c1 = (f32x4){0.f, 0.f, 0.f, 0.f};
#pragma unroll
    for (int ks = 0; ks < 3; ++ks) {
        const int ch = ks * 4 + lg;           // chunk 0..11
        bf16x8 a  = *(const bf16x8*)(xs + (w * 16 + lr) * 104 + ch * 8);
        bf16x8 b0 = *(const bf16x8*)(bt + lr * 104 + ch * 8);
        bf16x8 b1 = *(const bf16x8*)(bt + (16 + lr) * 104 + ch * 8);
        c0 = __builtin_amdgcn_mfma_f32_16x16x32_bf16(a, b0, c0, 0, 0, 0);
        c1 = __builtin_amdgcn_mfma_f32_16x16x32_bf16(a, b1, c1, 0, 0, 0);
    }

    const float bia0 = bias[lr];
    const float bia1 = bias[16 + lr];
#pragma unroll
    for (int r = 0; r < 4; ++r) {
        int nodeW = node0 + w * 16 + lg * 4 + r;
        if (nodeW < n) {
            catOut[(size_t)nodeW * 128 + lr]      = (u16)f2bf(fast_tanh(c0[r] + bia0));
            catOut[(size_t)nodeW * 128 + 16 + lr] = (u16)f2bf(fast_tanh(c1[r] + bia1));
        }
    }
}

// ---- head: one wave per pair, 256-dim dot (bf16 cat) + sigmoid ----
__global__ void k_head(const u16* __restrict__ cat, const int* __restrict__ uidx,
                       const int* __restrict__ iidx, const float* __restrict__ w,
                       const float* __restrict__ b, float* __restrict__ out, int B) {
    int p = blockIdx.x;
    if (p >= B) return;
    int lane = threadIdx.x;  // 0..63
    const u16* cu = cat + (size_t)uidx[p] * 128;
    const u16* ci = cat + (size_t)iidx[p] * 128;
    float s = 0.f;
    s = fmaf(bf2f(cu[lane]), w[lane], s);
    s = fmaf(bf2f(cu[lane + 64]), w[lane + 64], s);
    s = fmaf(bf2f(ci[lane]), w[lane + 128], s);
    s = fmaf(bf2f(ci[lane + 64]), w[lane + 192], s);
    for (int d = 32; d > 0; d >>= 1) s += __shfl_down(s, d, 64);
    if (lane == 0) out[p] = 1.f / (1.f + expf(-(s + b[0])));
}

extern "C" void kernel_launch(void* const* d_in, const int* in_sizes, int n_in,
                              void* d_out, int out_size, void* d_ws, size_t ws_size,
                              hipStream_t stream) {
    const float* x      = (const float*)d_in[0];
    const int*   src    = (const int*)d_in[1];
    const int*   dst    = (const int*)d_in[2];
    const int*   etype  = (const int*)d_in[3];
    const int*   uidx   = (const int*)d_in[4];
    const int*   iidx   = (const int*)d_in[5];
    const float* lin1_w = (const float*)d_in[22];
    const float* lin1_b = (const float*)d_in[23];

    const int N = in_sizes[0] / 64;
    const int E = in_sizes[1];
    const int B = in_sizes[4];
    const int NBUK = (N + BUK_W - 1) >> BUK_SH;

    // workspace carve-out (256B aligned)
    char* p = (char*)d_ws;
    auto alloc = [&](size_t bytes) -> void* {
        void* r = (void*)p;
        p += (bytes + 255) & ~(size_t)255;
        return r;
    };
    u32*   hb2     = (u32*)alloc((size_t)N * 32 * sizeof(u32));
    float* self0   = (float*)alloc((size_t)N * 32 * sizeof(float));
    u16*   cat     = (u16*)alloc((size_t)N * 128 * sizeof(u16));
    int*   rowptr  = (int*)alloc((size_t)(N + 1) * sizeof(int));
    u32*   epack   = (u32*)alloc((size_t)E * sizeof(u32));
    u32*   binned  = (u32*)alloc((size_t)E * sizeof(u32));
    int*   gBukCnt = (int*)alloc(1024 * sizeof(int));
    int*   gBukCur = (int*)alloc(1024 * sizeof(int));  // adjacent to gBukCnt
    int*   bukOff  = (int*)alloc(1025 * sizeof(int));

    // ---- CSR build (bucket pipeline) ----
    k_zero<<<8, 256, 0, stream>>>(gBukCnt, 2048);   // gBukCnt + gBukCur
    int ebGrid = (E + 2047) / 2048;
    k_buk_count<<<ebGrid, 256, 0, stream>>>(dst, gBukCnt, E);
    k_buk_scan<<<1, 1024, 0, stream>>>(gBukCnt, bukOff, NBUK);
    k_binscatter<<<ebGrid, 256, 0, stream>>>(src, dst, etype, bukOff, gBukCur,
                                             binned, E, NBUK);
    k_bucket_finalize<<<NBUK, 256, 0, stream>>>(binned, bukOff, rowptr, epack, N, E);

    const int tr_grid = (N + 63) / 64;

    // ---- layer 0: transform -> aggregate (x is 64-dim) ----
    k_transform3<64><<<tr_grid, 256, 0, stream>>>(
        x, 64, (const float*)d_in[6], (const float*)d_in[8], (const float*)d_in[9],
        hb2, self0, N);
    k_aggregate0<<<(N * 8 + 255) / 256, 256, 0, stream>>>(
        hb2, epack, rowptr, (const float*)d_in[7], self0, cat, N);

    // ---- layers 1-3: fused aggregate+transform ----
    for (int l = 1; l < 4; ++l) {
        k_layer_y<<<tr_grid, 256, 0, stream>>>(
            cat + (size_t)(l - 1) * 32, epack, rowptr,
            (const float*)d_in[7 + l * 4], (const float*)d_in[6 + l * 4],
            (const float*)d_in[8 + l * 4], (const float*)d_in[9 + l * 4],
            cat + (size_t)l * 32, N);
    }

    // ---- head ----
    k_head<<<B, 64, 0, stream>>>(cat, uidx, iidx, lin1_w, lin1_b, (float*)d_out, B);
}